// Round 5
// baseline (5418.453 us; speedup 1.0000x reference)
//
#include <hip/hip_runtime.h>
#include <math.h>

typedef short short8 __attribute__((ext_vector_type(8)));
typedef float f32x4 __attribute__((ext_vector_type(4)));

// ---------------- helpers ----------------
__device__ __forceinline__ float block_reduce(float v, float* red) {
  int tid = threadIdx.x;
  red[tid] = v; __syncthreads();
  for (int s = 128; s >= 1; s >>= 1) {
    if (tid < s) red[tid] += red[tid + s];
    __syncthreads();
  }
  float r = red[0];
  __syncthreads();
  return r;
}

// f32 -> (hi bf16, lo bf16). hi = round-half-up; lo = exact residual truncated.
__device__ __forceinline__ void cvt1(float x, unsigned short& h, unsigned short& l) {
  unsigned u = __float_as_uint(x);
  unsigned hb = (u + 0x8000u) & 0xffff0000u;
  h = (unsigned short)(hb >> 16);
  l = (unsigned short)(__float_as_uint(x - __uint_as_float(hb)) >> 16);
}

// pairwise-packed variant (elem a in low 16, b in high 16) — used by attention
__device__ __forceinline__ void cvt2(float a, float b, unsigned& hp, unsigned& lp) {
  unsigned ua = __float_as_uint(a), ub = __float_as_uint(b);
  unsigned ha = (ua + 0x8000u) & 0xffff0000u;
  unsigned hb = (ub + 0x8000u) & 0xffff0000u;
  float la = a - __uint_as_float(ha);
  float lb = b - __uint_as_float(hb);
  hp = (ha >> 16) | hb;
  lp = (__float_as_uint(la) >> 16) | (__float_as_uint(lb) & 0xffff0000u);
}

union U8 { unsigned u[4]; short8 s; };

__global__ __launch_bounds__(256) void sentinel_kernel(float* __restrict__ out, int n, float v) {
  int i = blockIdx.x * 256 + threadIdx.x;
  if (i < n) out[i] = v;
}

// ---------------- BatchNorm stats ----------------
__global__ __launch_bounds__(256) void bn_stats_kernel(
    const float* __restrict__ tok, const float* __restrict__ g,
    const float* __restrict__ bb, float* __restrict__ ss) {
  __shared__ float red[256];
  const int d = blockIdx.x;
  float sum = 0.f, sumsq = 0.f;
  for (int s = threadIdx.x; s < 4096; s += 256) {
    float v = tok[s * 64 + d];
    sum += v; sumsq += v * v;
  }
  sum = block_reduce(sum, red);
  sumsq = block_reduce(sumsq, red);
  if (threadIdx.x == 0) {
    float mu = sum * (1.f / 4096.f);
    float var = sumsq * (1.f / 4096.f) - mu * mu;
    float sc = g[d] * rsqrtf(fmaxf(var, 0.f) + 1e-5f);
    ss[d] = sc;
    ss[64 + d] = bb[d] - mu * sc;
  }
}

__global__ __launch_bounds__(256) void tn_kernel(
    const float* __restrict__ tok, const float* __restrict__ ss,
    float* __restrict__ tn) {
  int idx = blockIdx.x * 256 + threadIdx.x;
  int d = idx & 63;
  tn[idx] = tok[idx] * ss[d] + ss[64 + d];
}

__global__ __launch_bounds__(256) void reverse_kernel(
    const float* __restrict__ x0, float* __restrict__ x0r) {
  int idx = blockIdx.x * 256 + threadIdx.x;
  int row = idx >> 9, e = idx & 511;
  int b = row >> 10, t = row & 1023;
  x0r[idx] = x0[((size_t)((b << 10) + (1023 - t))) * 512 + e];
}

// ---------------- row LayerNorm, f32 out (N = 512 or 256) ----------------
__global__ __launch_bounds__(256) void ln_kernel(
    const float* __restrict__ x, const float* __restrict__ g,
    const float* __restrict__ b, float* __restrict__ out, int N) {
  __shared__ float red[256];
  const size_t r = blockIdx.x;
  const int tid = threadIdx.x;
  float v0 = x[r * N + tid];
  float v1 = (N > 256) ? x[r * N + 256 + tid] : 0.f;
  float sum = block_reduce(v0 + v1, red);
  float sumsq = block_reduce(v0 * v0 + v1 * v1, red);
  float mean = sum / (float)N;
  float var = sumsq / (float)N - mean * mean;
  float rs = rsqrtf(fmaxf(var, 0.f) + 1e-5f);
  out[r * N + tid] = (v0 - mean) * rs * g[tid] + b[tid];
  if (N > 256)
    out[r * N + 256 + tid] = (v1 - mean) * rs * g[256 + tid] + b[256 + tid];
}

// ---------------- row LayerNorm, N=512, bf16 hi/lo plane out ----------------
__global__ __launch_bounds__(256) void ln_pl(
    const float* __restrict__ x, const float* __restrict__ g,
    const float* __restrict__ b, unsigned short* __restrict__ oh,
    unsigned short* __restrict__ ol) {
  __shared__ float red[256];
  const size_t r = blockIdx.x;
  const int tid = threadIdx.x;
  float v0 = x[r * 512 + tid];
  float v1 = x[r * 512 + 256 + tid];
  float sum = block_reduce(v0 + v1, red);
  float sumsq = block_reduce(v0 * v0 + v1 * v1, red);
  float mean = sum * (1.f / 512.f);
  float var = sumsq * (1.f / 512.f) - mean * mean;
  float rs = rsqrtf(fmaxf(var, 0.f) + 1e-5f);
  float o0 = (v0 - mean) * rs * g[tid] + b[tid];
  float o1 = (v1 - mean) * rs * g[256 + tid] + b[256 + tid];
  unsigned short h0, l0, h1, l1;
  cvt1(o0, h0, l0); cvt1(o1, h1, l1);
  oh[r * 512 + tid] = h0;       ol[r * 512 + tid] = l0;
  oh[r * 512 + 256 + tid] = h1; ol[r * 512 + 256 + tid] = l1;
}

// ---------------- weight conversion: f32 [K][N] -> transposed planes [N][K] ----------------
// One layer per blockIdx.y (src layer stride K*N, dst layer stride dls elems).
__global__ __launch_bounds__(256) void convw(
    const float* __restrict__ W, unsigned short* __restrict__ hi,
    unsigned short* __restrict__ lo, int K, int N, long dls) {
  int id = blockIdx.x * 256 + threadIdx.x;
  int total = (K >> 3) * N;
  if (id >= total) return;
  int c = id / N, n = id - c * N;
  const float* Wp = W + (size_t)blockIdx.y * K * N;
  size_t doff = (size_t)blockIdx.y * dls + (size_t)n * K + c * 8;
  unsigned short h8[8], l8[8];
#pragma unroll
  for (int j = 0; j < 8; ++j) {
    float xv = Wp[(size_t)(c * 8 + j) * N + n];
    cvt1(xv, h8[j], l8[j]);
  }
  uint4 hv = make_uint4(h8[0] | ((unsigned)h8[1] << 16), h8[2] | ((unsigned)h8[3] << 16),
                        h8[4] | ((unsigned)h8[5] << 16), h8[6] | ((unsigned)h8[7] << 16));
  uint4 lv = make_uint4(l8[0] | ((unsigned)l8[1] << 16), l8[2] | ((unsigned)l8[3] << 16),
                        l8[4] | ((unsigned)l8[5] << 16), l8[6] | ((unsigned)l8[7] << 16));
  *reinterpret_cast<uint4*>(hi + doff) = hv;
  *reinterpret_cast<uint4*>(lo + doff) = lv;
}

// --------- small GEMM (f32): out[M,N] = A@W + bias (act) ---------
#define BK 16
template <int ACT>  // 0 none, 1 gelu(exact), 2 tanh
__global__ __launch_bounds__(256) void gemm3(
    const float* __restrict__ A, const float* __restrict__ W,
    const float* __restrict__ bias, const float* resid,
    float* out, int M, int N, int K) {
  __shared__ float As[BK][64 + 4];
  __shared__ float Bs[BK][64 + 4];
  const int tid = threadIdx.x;
  const int tx = tid & 15, ty = tid >> 4;
  const int n0 = blockIdx.x * 64, m0 = blockIdx.y * 64;
  float acc[4][4] = {};
  for (int k0 = 0; k0 < K; k0 += BK) {
    {
      int m = tid >> 2, kq = tid & 3;
      float4 a4 = *reinterpret_cast<const float4*>(A + (size_t)(m0 + m) * K + k0 + kq * 4);
      As[kq * 4 + 0][m] = a4.x; As[kq * 4 + 1][m] = a4.y;
      As[kq * 4 + 2][m] = a4.z; As[kq * 4 + 3][m] = a4.w;
    }
    {
      int kk = tid >> 4, nq = tid & 15;
      float4 b4 = *reinterpret_cast<const float4*>(W + (size_t)(k0 + kk) * N + n0 + nq * 4);
      Bs[kk][nq * 4 + 0] = b4.x; Bs[kk][nq * 4 + 1] = b4.y;
      Bs[kk][nq * 4 + 2] = b4.z; Bs[kk][nq * 4 + 3] = b4.w;
    }
    __syncthreads();
#pragma unroll
    for (int kq = 0; kq < BK; ++kq) {
      float4 av = *reinterpret_cast<const float4*>(&As[kq][ty * 4]);
      float4 bv = *reinterpret_cast<const float4*>(&Bs[kq][tx * 4]);
      acc[0][0] += av.x * bv.x; acc[0][1] += av.x * bv.y; acc[0][2] += av.x * bv.z; acc[0][3] += av.x * bv.w;
      acc[1][0] += av.y * bv.x; acc[1][1] += av.y * bv.y; acc[1][2] += av.y * bv.z; acc[1][3] += av.y * bv.w;
      acc[2][0] += av.z * bv.x; acc[2][1] += av.z * bv.y; acc[2][2] += av.z * bv.z; acc[2][3] += av.z * bv.w;
      acc[3][0] += av.w * bv.x; acc[3][1] += av.w * bv.y; acc[3][2] += av.w * bv.z; acc[3][3] += av.w * bv.w;
    }
    __syncthreads();
  }
#pragma unroll
  for (int i = 0; i < 4; ++i) {
    int m = m0 + ty * 4 + i;
#pragma unroll
    for (int j = 0; j < 4; ++j) {
      int n = n0 + tx * 4 + j;
      float v = acc[i][j] + bias[n];
      if (resid) v += resid[(size_t)m * N + n];
      if (ACT == 1) v = 0.5f * v * (1.f + erff(v * 0.70710678118654752f));
      if (ACT == 2) v = tanhf(v);
      out[(size_t)m * N + n] = v;
    }
  }
}

// --------- MFMA GEMM over pre-split bf16 planes. 128x128x32 tiles, 4 waves. ---------
// A planes [M][K], B planes [N][K] (transposed weights), all row-major ushort.
// Staging permutes 16B slots by slot^((row>>1)&3): frag ds_read_b128 <=2-way bank alias.
// 2-phase reg pipeline; XCD-aware block swizzle (grids % 8 == 0).
// ACT: 0 none, 1 gelu, 2 tanh. OUTMODE: 0 f32, 1 planes, 2 both.
// ATOMIC: f32 atomicAdd into Cf (bias added by z==0). BIAS3: b0/b1/b2 512-wide sections.
template <int ACT, int OUTMODE, int ATOMIC, int BIAS3>
__global__ __launch_bounds__(256, 3) void gemm_bf(
    const unsigned short* __restrict__ Ahp, const unsigned short* __restrict__ Alp,
    const unsigned short* __restrict__ Bhp, const unsigned short* __restrict__ Blp,
    const float* __restrict__ b0, const float* __restrict__ b1, const float* __restrict__ b2,
    float* __restrict__ Cf, unsigned short* __restrict__ Chp, unsigned short* __restrict__ Clp,
    int M, int N, int K, int KZ) {
  __shared__ __align__(16) unsigned short LAh[4096];
  __shared__ __align__(16) unsigned short LAl[4096];
  __shared__ __align__(16) unsigned short LBh[4096];
  __shared__ __align__(16) unsigned short LBl[4096];
  const int tid = threadIdx.x;
  const int lane = tid & 63, wid = tid >> 6;
  const int wr = wid >> 1, wc = wid & 1;
  const int lr = lane & 15, lq = lane >> 4;

  // XCD swizzle over (x,y)
  const int gx = gridDim.x;
  int lin = blockIdx.y * gx + blockIdx.x;
  int qch = (gx * gridDim.y) >> 3;
  int swz = (lin & 7) * qch + (lin >> 3);
  const int nb = swz % gx, mb = swz / gx;
  const int n0 = nb * 128, m0 = mb * 128;
  const int kbase = blockIdx.z * KZ, kend = kbase + KZ;

  f32x4 acc[4][4];
#pragma unroll
  for (int i = 0; i < 4; ++i)
#pragma unroll
    for (int j = 0; j < 4; ++j) { acc[i][j][0] = 0.f; acc[i][j][1] = 0.f; acc[i][j][2] = 0.f; acc[i][j][3] = 0.f; }

  // staging coords: 2 chunks/thread/plane; chunk t covers rows t*64..t*64+63
  const int rA = tid >> 2, phys = tid & 3;
  const int row0 = rA, row1 = 64 + rA;
  const int slot0 = phys ^ ((row0 >> 1) & 3);
  const int slot1 = phys ^ ((row1 >> 1) & 3);
  const int ld0 = rA * 32 + phys * 8;
  const int ld1 = (64 + rA) * 32 + phys * 8;

  uint4 rg[8];
  const unsigned short* aH = Ahp + (size_t)m0 * K;
  const unsigned short* aL = Alp + (size_t)m0 * K;
  const unsigned short* bH = Bhp + (size_t)n0 * K;
  const unsigned short* bL = Blp + (size_t)n0 * K;

  auto issue = [&](int k0) {
    rg[0] = *reinterpret_cast<const uint4*>(aH + (size_t)row0 * K + k0 + slot0 * 8);
    rg[1] = *reinterpret_cast<const uint4*>(aH + (size_t)row1 * K + k0 + slot1 * 8);
    rg[2] = *reinterpret_cast<const uint4*>(aL + (size_t)row0 * K + k0 + slot0 * 8);
    rg[3] = *reinterpret_cast<const uint4*>(aL + (size_t)row1 * K + k0 + slot1 * 8);
    rg[4] = *reinterpret_cast<const uint4*>(bH + (size_t)row0 * K + k0 + slot0 * 8);
    rg[5] = *reinterpret_cast<const uint4*>(bH + (size_t)row1 * K + k0 + slot1 * 8);
    rg[6] = *reinterpret_cast<const uint4*>(bL + (size_t)row0 * K + k0 + slot0 * 8);
    rg[7] = *reinterpret_cast<const uint4*>(bL + (size_t)row1 * K + k0 + slot1 * 8);
  };

  issue(kbase);
  for (int k0 = kbase; k0 < kend; k0 += 32) {
    *reinterpret_cast<uint4*>(LAh + ld0) = rg[0];
    *reinterpret_cast<uint4*>(LAh + ld1) = rg[1];
    *reinterpret_cast<uint4*>(LAl + ld0) = rg[2];
    *reinterpret_cast<uint4*>(LAl + ld1) = rg[3];
    *reinterpret_cast<uint4*>(LBh + ld0) = rg[4];
    *reinterpret_cast<uint4*>(LBh + ld1) = rg[5];
    *reinterpret_cast<uint4*>(LBl + ld0) = rg[6];
    *reinterpret_cast<uint4*>(LBl + ld1) = rg[7];
    __syncthreads();
    if (k0 + 32 < kend) issue(k0 + 32);
    short8 ah[4], al[4], bh[4], bl[4];
#pragma unroll
    for (int mi = 0; mi < 4; ++mi) {
      int row = wr * 64 + mi * 16 + lr;
      int off = row * 32 + (lq ^ ((row >> 1) & 3)) * 8;
      ah[mi] = *reinterpret_cast<const short8*>(&LAh[off]);
      al[mi] = *reinterpret_cast<const short8*>(&LAl[off]);
    }
#pragma unroll
    for (int ni = 0; ni < 4; ++ni) {
      int n = wc * 64 + ni * 16 + lr;
      int off = n * 32 + (lq ^ ((n >> 1) & 3)) * 8;
      bh[ni] = *reinterpret_cast<const short8*>(&LBh[off]);
      bl[ni] = *reinterpret_cast<const short8*>(&LBl[off]);
    }
#pragma unroll
    for (int mi = 0; mi < 4; ++mi)
#pragma unroll
      for (int ni = 0; ni < 4; ++ni) {
        acc[mi][ni] = __builtin_amdgcn_mfma_f32_16x16x32_bf16(ah[mi], bh[ni], acc[mi][ni], 0, 0, 0);
        acc[mi][ni] = __builtin_amdgcn_mfma_f32_16x16x32_bf16(ah[mi], bl[ni], acc[mi][ni], 0, 0, 0);
        acc[mi][ni] = __builtin_amdgcn_mfma_f32_16x16x32_bf16(al[mi], bh[ni], acc[mi][ni], 0, 0, 0);
      }
    __syncthreads();
  }

  // ---- epilogue ----
  const float* bsec = b0;
  int bof = 0;
  if (BIAS3) { bsec = (n0 < 512) ? b0 : (n0 < 1024 ? b1 : b2); bof = (n0 & 511) - n0; }
#pragma unroll
  for (int mi = 0; mi < 4; ++mi) {
#pragma unroll
    for (int r = 0; r < 4; ++r) {
      int grow = m0 + wr * 64 + mi * 16 + lq * 4 + r;
#pragma unroll
      for (int ni = 0; ni < 4; ++ni) {
        int col = n0 + wc * 64 + ni * 16 + lr;
        float v = acc[mi][ni][r];
        float bias = BIAS3 ? bsec[col + bof] : b0[col];
        if (ATOMIC) {
          if (blockIdx.z == 0) v += bias;
          atomicAdd(&Cf[(size_t)grow * N + col], v);
        } else {
          v += bias;
          if (ACT == 1) v = 0.5f * v * (1.f + erff(v * 0.70710678118654752f));
          if (ACT == 2) v = tanhf(v);
          if (OUTMODE == 0 || OUTMODE == 2) Cf[(size_t)grow * N + col] = v;
          if (OUTMODE >= 1) {
            unsigned short hv, lv;
            cvt1(v, hv, lv);
            Chp[(size_t)grow * N + col] = hv;
            Clp[(size_t)grow * N + col] = lv;
          }
        }
      }
    }
  }
}

// ---------------- attention: MFMA flash, bf16x3, 64x64 tiles ----------------
// Reads fused qkv f32 buffer [4096][1536] (q|k|v); writes yb as bf16 hi/lo planes.
__global__ __launch_bounds__(256, 2) void attn_mfma(
    const float* __restrict__ qkv, const float* __restrict__ mask,
    unsigned short* __restrict__ ybh, unsigned short* __restrict__ ybl, int rev) {
  __shared__ __align__(16) unsigned SH[4096];       // 16KB: Q staging, then V^T hi/lo
  __shared__ __align__(16) unsigned KhL[2048];      // 8KB  K hi
  __shared__ __align__(16) unsigned KlL[2048];      // 8KB  K lo
  __shared__ float PU[64 * 68];                     // 17KB P (f32)
  __shared__ float km[64];
  unsigned* VhL = SH;
  unsigned* VlL = SH + 2048;

  const int tid = threadIdx.x;
  const int lane = tid & 63, w = tid >> 6;
  const int lr = lane & 15, lq = lane >> 4;

  const int id = blockIdx.x;          // complementary-pair mapping
  const int top = id >> 8;
  const int r5 = id & 255;
  const int qt = top ? (15 - (r5 >> 4)) : (r5 >> 4);
  const int bh_ = (r5 & 15) | (top << 4);
  const int b = bh_ >> 3, h = bh_ & 7;

  // ---- stage Q (scaled 1/8) into SH, swizzled ----
  {
    const float* qp = qkv + (size_t)(b * 1024 + qt * 64) * 1536 + h * 64;
    int row = tid >> 2, f4 = tid & 3;
#pragma unroll
    for (int j = 0; j < 4; ++j) {
      int dk = f4 * 4 + j * 16;
      float4 a = *reinterpret_cast<const float4*>(qp + (size_t)row * 1536 + dk);
      unsigned h0, l0, h1, l1;
      cvt2(a.x * 0.125f, a.y * 0.125f, h0, l0);
      cvt2(a.z * 0.125f, a.w * 0.125f, h1, l1);
      int phys = (dk >> 3) ^ (row & 7);
      int off = row * 32 + phys * 4 + (f4 & 1) * 2;
      *reinterpret_cast<uint2*>(&SH[off]) = make_uint2(h0, h1);
      *reinterpret_cast<uint2*>(&KhL[off]) = make_uint2(l0, l1);  // temp: Q-lo in KhL
    }
  }
  __syncthreads();
  short8 qa_h[2], qa_l[2];
#pragma unroll
  for (int ks = 0; ks < 2; ++ks) {
    int row = w * 16 + lr;
    int phys = (lq + ks * 4) ^ (row & 7);
    qa_h[ks] = *reinterpret_cast<const short8*>(&SH[row * 32 + phys * 4]);
    qa_l[ks] = *reinterpret_cast<const short8*>(&KhL[row * 32 + phys * 4]);
  }
  __syncthreads();  // SH/KhL now free for V^T / K tiles

  float m_[4], l_[4] = {0.f, 0.f, 0.f, 0.f};
  f32x4 o_[4];
#pragma unroll
  for (int r = 0; r < 4; ++r) m_[r] = -1e30f;
#pragma unroll
  for (int df = 0; df < 4; ++df) { o_[df][0] = 0.f; o_[df][1] = 0.f; o_[df][2] = 0.f; o_[df][3] = 0.f; }

  for (int kt = 0; kt <= qt; ++kt) {
    const float* kp = qkv + (size_t)(b * 1024 + kt * 64) * 1536 + 512 + h * 64;
    const float* vp = qkv + (size_t)(b * 1024 + kt * 64) * 1536 + 1024 + h * 64;
    // ---- stage K (row-major, swizzled) ----
    {
      int row = tid >> 2, f4 = tid & 3;
#pragma unroll
      for (int j = 0; j < 4; ++j) {
        int dk = f4 * 4 + j * 16;
        float4 a = *reinterpret_cast<const float4*>(kp + (size_t)row * 1536 + dk);
        unsigned h0, l0, h1, l1;
        cvt2(a.x, a.y, h0, l0);
        cvt2(a.z, a.w, h1, l1);
        int phys = (dk >> 3) ^ (row & 7);
        int off = row * 32 + phys * 4 + (f4 & 1) * 2;
        *reinterpret_cast<uint2*>(&KhL[off]) = make_uint2(h0, h1);
        *reinterpret_cast<uint2*>(&KlL[off]) = make_uint2(l0, l1);
      }
    }
    // ---- stage V^T (key-pairs packed per uint, swizzled) ----
    {
      int d = tid & 63, g = tid >> 6;
#pragma unroll
      for (int j = 0; j < 8; ++j) {
        int kpair = (g + j * 4 + (d >> 3)) & 31;
        float v0 = vp[(size_t)(kpair * 2) * 1536 + d];
        float v1 = vp[(size_t)(kpair * 2 + 1) * 1536 + d];
        unsigned hh, ll;
        cvt2(v0, v1, hh, ll);
        int phys = (kpair >> 2) ^ (d & 7);
        int off = d * 32 + phys * 4 + (kpair & 3);
        VhL[off] = hh; VlL[off] = ll;
      }
    }
    if (tid < 64) {
      int s = kt * 64 + tid;
      km[tid] = mask[b * 1024 + (rev ? (1023 - s) : s)];
    }
    __syncthreads();

    // ---- S = Q K^T (x3 MFMA) ----
    f32x4 sacc[4];
#pragma unroll
    for (int kf = 0; kf < 4; ++kf) { sacc[kf][0] = 0.f; sacc[kf][1] = 0.f; sacc[kf][2] = 0.f; sacc[kf][3] = 0.f; }
#pragma unroll
    for (int ks = 0; ks < 2; ++ks) {
#pragma unroll
      for (int kf = 0; kf < 4; ++kf) {
        int col = kf * 16 + lr;
        int phys = (lq + ks * 4) ^ (lr & 7);
        short8 kbh = *reinterpret_cast<const short8*>(&KhL[col * 32 + phys * 4]);
        short8 kbl = *reinterpret_cast<const short8*>(&KlL[col * 32 + phys * 4]);
        sacc[kf] = __builtin_amdgcn_mfma_f32_16x16x32_bf16(qa_h[ks], kbh, sacc[kf], 0, 0, 0);
        sacc[kf] = __builtin_amdgcn_mfma_f32_16x16x32_bf16(qa_h[ks], kbl, sacc[kf], 0, 0, 0);
        sacc[kf] = __builtin_amdgcn_mfma_f32_16x16x32_bf16(qa_l[ks], kbh, sacc[kf], 0, 0, 0);
      }
    }

    // ---- online softmax in registers ----
    const bool diag = (kt == qt);
    float kmv[4];
#pragma unroll
    for (int kf = 0; kf < 4; ++kf) kmv[kf] = km[kf * 16 + lr];
#pragma unroll
    for (int r = 0; r < 4; ++r) {
      int fi = (w * 16 + lq * 4 + r) >> 3;
      float mt = -1e30f;
#pragma unroll
      for (int kf = 0; kf < 4; ++kf) {
        int key = kf * 16 + lr;
        bool ok = (kmv[kf] > 0.f) && (!diag || ((key >> 3) <= fi));
        float x = ok ? sacc[kf][r] : -1e30f;
        sacc[kf][r] = x;
        mt = fmaxf(mt, x);
      }
      mt = fmaxf(mt, __shfl_xor(mt, 1, 16));
      mt = fmaxf(mt, __shfl_xor(mt, 2, 16));
      mt = fmaxf(mt, __shfl_xor(mt, 4, 16));
      mt = fmaxf(mt, __shfl_xor(mt, 8, 16));
      float mn = fmaxf(m_[r], mt);
      float al = __expf(m_[r] - mn);
      m_[r] = mn;
      float rs = 0.f;
#pragma unroll
      for (int kf = 0; kf < 4; ++kf) {
        float sv = sacc[kf][r];
        float p = (sv > -1e29f) ? __expf(sv - mn) : 0.f;
        sacc[kf][r] = p;
        rs += p;
      }
      rs += __shfl_xor(rs, 1, 16);
      rs += __shfl_xor(rs, 2, 16);
      rs += __shfl_xor(rs, 4, 16);
      rs += __shfl_xor(rs, 8, 16);
      l_[r] = l_[r] * al + rs;
#pragma unroll
      for (int df = 0; df < 4; ++df) o_[df][r] *= al;
    }
    // ---- write P (f32, 68-stride) ----
#pragma unroll
    for (int kf = 0; kf < 4; ++kf)
#pragma unroll
      for (int r = 0; r < 4; ++r)
        PU[(w * 16 + lq * 4 + r) * 68 + kf * 16 + lr] = sacc[kf][r];
    __syncthreads();

    // ---- O += P V (x3 MFMA) ----
#pragma unroll
    for (int ks = 0; ks < 2; ++ks) {
      const float* pp = &PU[(w * 16 + lr) * 68 + ks * 32 + lq * 8];
      float4 p0 = *reinterpret_cast<const float4*>(pp);
      float4 p1 = *reinterpret_cast<const float4*>(pp + 4);
      U8 th, tl;
      cvt2(p0.x, p0.y, th.u[0], tl.u[0]);
      cvt2(p0.z, p0.w, th.u[1], tl.u[1]);
      cvt2(p1.x, p1.y, th.u[2], tl.u[2]);
      cvt2(p1.z, p1.w, th.u[3], tl.u[3]);
      short8 pa_h = th.s, pa_l = tl.s;
#pragma unroll
      for (int df = 0; df < 4; ++df) {
        int col = df * 16 + lr;
        int phys = (lq + ks * 4) ^ (lr & 7);
        short8 vbh = *reinterpret_cast<const short8*>(&VhL[col * 32 + phys * 4]);
        short8 vbl = *reinterpret_cast<const short8*>(&VlL[col * 32 + phys * 4]);
        o_[df] = __builtin_amdgcn_mfma_f32_16x16x32_bf16(pa_h, vbh, o_[df], 0, 0, 0);
        o_[df] = __builtin_amdgcn_mfma_f32_16x16x32_bf16(pa_h, vbl, o_[df], 0, 0, 0);
        o_[df] = __builtin_amdgcn_mfma_f32_16x16x32_bf16(pa_l, vbh, o_[df], 0, 0, 0);
      }
    }
    __syncthreads();
  }

  // ---- normalize + write planes ----
#pragma unroll
  for (int r = 0; r < 4; ++r) {
    float inv = 1.f / fmaxf(l_[r], 1e-30f);
    int qrow = qt * 64 + w * 16 + lq * 4 + r;
#pragma unroll
    for (int df = 0; df < 4; ++df) {
      float val = o_[df][r] * inv;
      unsigned short hv, lv;
      cvt1(val, hv, lv);
      size_t idx = (size_t)(b * 1024 + qrow) * 512 + h * 64 + df * 16 + lr;
      ybh[idx] = hv; ybl[idx] = lv;
    }
  }
}

// ---------------- frame mean (+ FLOAT32 output write) ----------------
__global__ __launch_bounds__(256) void frame_mean_kernel(
    const float* __restrict__ xo, float* __restrict__ xf,
    float* __restrict__ outf) {
  int row = blockIdx.x;       // b*128+tf
  int o = threadIdx.x;
  float s = 0.f;
#pragma unroll
  for (int c = 0; c < 8; ++c) s += xo[((size_t)row * 8 + c) * 256 + o];
  s *= 0.125f;
  xf[row * 256 + o] = s;
  if (outf) outf[row * 256 + o] = s;
}

// ---------------- losses ----------------
__global__ __launch_bounds__(256) void loss_reg_kernel(
    const float* __restrict__ pd, const float* __restrict__ tok,
    const float* __restrict__ mask, float* __restrict__ acc, int rev) {
  __shared__ float red[256];
  float local = 0.f;
  for (int idx = blockIdx.x * 256 + threadIdx.x; idx < 260096; idx += gridDim.x * 256) {
    int b = idx / 65024, r2 = idx % 65024;
    int t = r2 >> 6, d = r2 & 63;
    float pred = pd[((size_t)((b << 10) + t)) * 64 + d] * mask[(b << 10) + t];
    int tt = rev ? (1015 - t) : (t + 8);
    float tgt = tok[((size_t)((b << 10) + tt)) * 64 + d] * mask[(b << 10) + tt];
    float df = pred - tgt;
    local += df * df;
  }
  float s = block_reduce(local, red);
  if (threadIdx.x == 0) atomicAdd(acc, s);
}

__global__ __launch_bounds__(256) void loss_fr_kernel(
    const float* __restrict__ pf, const float* __restrict__ tok,
    const float* __restrict__ mask, float* __restrict__ acc, int rev) {
  __shared__ float red[256];
  float local = 0.f;
  for (int idx = blockIdx.x * 256 + threadIdx.x; idx < 260096; idx += gridDim.x * 256) {
    int b = idx / 65024, r2 = idx % 65024;
    int i = r2 >> 9, u = r2 & 511;
    float pred = pf[((size_t)(b * 128 + i)) * 512 + u];
    int c = u >> 6;
    int t = rev ? ((126 - i) * 8 + c) : ((i + 1) * 8 + c);
    float tgt = tok[((size_t)((b << 10) + t)) * 64 + (u & 63)] * mask[(b << 10) + t];
    float df = pred - tgt;
    local += df * df;
  }
  float s = block_reduce(local, red);
  if (threadIdx.x == 0) atomicAdd(acc, s);
}

__global__ void finalize_kernel(const float* __restrict__ acc, float* __restrict__ out) {
  int i = threadIdx.x;
  if (i < 4) out[131072 + i] = acc[i] * (1.0f / 260096.0f);
}

extern "C" void kernel_launch(void* const* d_in, const int* in_sizes, int n_in,
                              void* d_out, int out_size, void* d_ws, size_t ws_size,
                              hipStream_t stream) {
  float* ws = (float*)d_ws;
  const size_t OFF_SS   = 0;
  const size_t OFF_LACC = 128;
  const size_t OFF_TN   = 256;
  const size_t OFF_X0   = 262400;
  const size_t OFF_X0R  = 2359552;
  const size_t OFF_X    = 4456704;
  const size_t OFF_HPL  = 6553856;    // h planes (hi 1048576 fl, lo 1048576 fl)
  const size_t OFF_QKV  = 8651008;    // qkv f32 6291456 fl; u planes alias
  const size_t OFF_YB   = 14942464;   // yb planes 2097152 fl
  const size_t OFF_XO   = 17039616;   // f32 1048576
  const size_t OFF_XOPL = 18088192;   // xo planes 1048576 fl
  const size_t OFF_HD   = 19136768;
  const size_t OFF_HD2  = 20185344;
  const size_t OFF_PD   = 21233920;
  const size_t OFF_XF   = 21496064;
  const size_t OFF_HF   = 21627136;
  const size_t OFF_HF2  = 21758208;
  const size_t OFF_PF   = 21889280;
  const size_t OFF_WB   = 22151424;
  const size_t TOTAL_MIN = OFF_WB + 1048576;    // JIT scratch mode (~92.8 MB)
  const size_t TOTAL_BIG = OFF_WB + 19070976;   // full weight-plane mode (~165 MB)

  float* ss   = ws + OFF_SS;
  float* lacc = ws + OFF_LACC;
  float* tn   = ws + OFF_TN;
  float* x0   = ws + OFF_X0;
  float* x0r  = ws + OFF_X0R;
  float* x    = ws + OFF_X;
  unsigned short* hh = (unsigned short*)(ws + OFF_HPL);
  unsigned short* hl = hh + 2097152;
  float* qkv  = ws + OFF_QKV;
  unsigned short* uh = (unsigned short*)(ws + OFF_QKV);   // alias (MLP phase only)
  unsigned short* ul = uh + 8388608;
  unsigned short* ybh = (unsigned short*)(ws + OFF_YB);
  unsigned short* ybl = ybh + 2097152;
  float* xo   = ws + OFF_XO;
  unsigned short* xoh = (unsigned short*)(ws + OFF_XOPL);
  unsigned short* xol = xoh + 1048576;
  float* hd   = ws + OFF_HD;
  float* hd2  = ws + OFF_HD2;
  float* pd   = ws + OFF_PD;
  float* xf   = ws + OFF_XF;
  float* hf   = ws + OFF_HF;
  float* hf2  = ws + OFF_HF2;
  float* pf   = ws + OFF_PF;
  unsigned short* wb16 = (unsigned short*)(ws + OFF_WB);
  float* out_f = (float*)d_out;   // OUTPUT IS FLOAT32

  static const int EXPECTED[39] = {
      262144, 4096, 4096, 64, 64, 32768, 512, 3072, 3072, 3072, 3072,
      1572864, 3072, 1572864, 3072, 1572864, 3072, 1572864, 3072,
      6291456, 12288, 6291456, 3072, 512, 512, 131072, 256, 65536, 256,
      256, 256, 16384, 64, 65536, 256, 256, 256, 131072, 512};
  bool manifest_ok = (n_in == 39) && (ws_size >= TOTAL_MIN * sizeof(float));
  if (manifest_ok)
    for (int i = 0; i < 39; ++i)
      if (in_sizes[i] != EXPECTED[i]) { manifest_ok = false; break; }
  if (!manifest_ok) {
    hipLaunchKernelGGL(sentinel_kernel, dim3((out_size + 255) / 256), dim3(256), 0, stream,
                       out_f, out_size, 2000.0f);
    return;
  }
  const bool bigws = ws_size >= TOTAL_BIG * sizeof(float);

  const float* tok    = (const float*)d_in[0];
  const float* mask   = (const float*)d_in[2];
  const float* bn_g   = (const float*)d_in[3];
  const float* bn_b   = (const float*)d_in[4];
  const float* We     = (const float*)d_in[5];
  const float* be     = (const float*)d_in[6];
  const float* ln1_g  = (const float*)d_in[7];
  const float* ln1_b  = (const float*)d_in[8];
  const float* ln2_g  = (const float*)d_in[9];
  const float* ln2_b  = (const float*)d_in[10];
  const float* Wq     = (const float*)d_in[11];
  const float* bq     = (const float*)d_in[12];
  const float* Wk     = (const float*)d_in[13];
  const float* bk     = (const float*)d_in[14];
  const float* Wv     = (const float*)d_in[15];
  const float* bv     = (const float*)d_in[16];
  const float* Wo     = (const float*)d_in[17];
  const float* bo     = (const float*)d_in[18];
  const float* W1     = (const float*)d_in[19];
  const float* b1     = (const float*)d_in[20];
  const float* W2     = (const float*)d_in[21];
  const float* b2     = (const float*)d_in[22];
  const float* lnf_g  = (const float*)d_in[23];
  const float* lnf_b  = (const float*)d_in[24];
  const float* Wp     = (const float*)d_in[25];
  const float* bp     = (const float*)d_in[26];
  const float* Wd1    = (const float*)d_in[27];
  const float* bd1    = (const float*)d_in[28];
  const float* lnd_g  = (const float*)d_in[29];
  const float* lnd_b  = (const float*)d_in[30];
  const float* Wd2    = (const float*)d_in[31];
  const float* bd2    = (const float*)d_in[32];
  const float* Wf1    = (const float*)d_in[33];
  const float* bf1    = (const float*)d_in[34];
  const float* lnfr_g = (const float*)d_in[35];
  const float* lnfr_b = (const float*)d_in[36];
  const float* Wf2    = (const float*)d_in[37];
  const float* bf2    = (const float*)d_in[38];

  // weight-plane pointers (big mode), ushort offsets
  unsigned short* wqkv_h = wb16;
  unsigned short* wqkv_l = wb16 + 4718592;
  unsigned short* wo_h   = wb16 + 9437184;
  unsigned short* wo_l   = wb16 + 11010048;
  unsigned short* w1_h   = wb16 + 12582912;
  unsigned short* w1_l   = wb16 + 18874368;
  unsigned short* w2_h   = wb16 + 25165824;
  unsigned short* w2_l   = wb16 + 31457280;
  unsigned short* wp_h   = wb16 + 37748736;
  unsigned short* wp_l   = wb16 + 37879808;
  unsigned short* wd1_h  = wb16 + 38010880;
  unsigned short* wd1_l  = wb16 + 38076416;
  unsigned short* scr    = wb16;   // JIT scratch (small mode)

  auto G = [&](int act, const float* A, const float* W, const float* bias,
               const float* resid, float* out, int M, int N, int K) {
    dim3 g(N / 64, M / 64), b(256);
    if (act == 0) hipLaunchKernelGGL((gemm3<0>), g, b, 0, stream, A, W, bias, resid, out, M, N, K);
    else if (act == 1) hipLaunchKernelGGL((gemm3<1>), g, b, 0, stream, A, W, bias, resid, out, M, N, K);
    else hipLaunchKernelGGL((gemm3<2>), g, b, 0, stream, A, W, bias, resid, out, M, N, K);
  };
  auto CONV = [&](const float* W, unsigned short* hi, unsigned short* lo,
                  int K, int N, int layers, long dls) {
    int blocks = ((K >> 3) * N + 255) / 256;
    hipLaunchKernelGGL(convw, dim3(blocks, layers), dim3(256), 0, stream, W, hi, lo, K, N, dls);
  };

  hipMemsetAsync(lacc, 0, 4 * sizeof(float), stream);
  if (bigws) {  // one-time full weight conversion
    CONV(Wq, wqkv_h,          wqkv_l,          512, 512, 6, 786432);
    CONV(Wk, wqkv_h + 262144, wqkv_l + 262144, 512, 512, 6, 786432);
    CONV(Wv, wqkv_h + 524288, wqkv_l + 524288, 512, 512, 6, 786432);
    CONV(Wo, wo_h, wo_l, 512, 512, 6, 262144);
    CONV(W1, w1_h, w1_l, 512, 2048, 6, 1048576);
    CONV(W2, w2_h, w2_l, 2048, 512, 6, 1048576);
    CONV(Wp, wp_h, wp_l, 512, 256, 1, 0);
    CONV(Wd1, wd1_h, wd1_l, 256, 256, 1, 0);
  }
  hipLaunchKernelGGL(bn_stats_kernel, dim3(64), dim3(256), 0, stream, tok, bn_g, bn_b, ss);
  hipLaunchKernelGGL(tn_kernel, dim3(1024), dim3(256), 0, stream, tok, ss, tn);
  G(0, tn, We, be, nullptr, x0, 4096, 512, 64);
  hipLaunchKernelGGL(reverse_kernel, dim3(8192), dim3(256), 0, stream, x0, x0r);

  for (int dir = 0; dir < 2; ++dir) {
    const float* xin = dir ? x0r : x0;
    for (int l = 0; l < 6; ++l) {
      const float* xl = (l == 0) ? xin : x;
      hipLaunchKernelGGL(ln_pl, dim3(4096), dim3(256), 0, stream,
                         xl, ln1_g + l * 512, ln1_b + l * 512, hh, hl);
      // fused QKV GEMM, N=1536
      const unsigned short *pqh, *pql;
      if (bigws) { pqh = wqkv_h + (size_t)l * 786432; pql = wqkv_l + (size_t)l * 786432; }
      else {
        CONV(Wq + (size_t)l * 262144, scr,          scr + 786432,          512, 512, 1, 0);
        CONV(Wk + (size_t)l * 262144, scr + 262144, scr + 786432 + 262144, 512, 512, 1, 0);
        CONV(Wv + (size_t)l * 262144, scr + 524288, scr + 786432 + 524288, 512, 512, 1, 0);
        pqh = scr; pql = scr + 786432;
      }
      hipLaunchKernelGGL((gemm_bf<0, 0, 0, 1>), dim3(12, 32, 1), dim3(256), 0, stream,
                         hh, hl, pqh, pql, bq + l * 512, bk + l * 512, bv + l * 512,
                         qkv, nullptr, nullptr, 4096, 1536, 512, 512);
      // seed x with the residual for layer 0
      if (l == 0)
        hipMemcpyAsync(x, xin, 2097152 * sizeof(float), hipMemcpyDeviceToDevice, stream);
      hipLaunchKernelGGL(attn_mfma, dim3(512), dim3(256), 0, stream, qkv, mask, ybh, ybl, dir);
      // O-proj: split-K=2, atomicAdd into x (x pre-holds residual)
      const unsigned short *poh, *pol;
      if (bigws) { poh = wo_h + (size_t)l * 262144; pol = wo_l + (size_t)l * 262144; }
      else {
        CONV(Wo + (size_t)l * 262144, scr, scr + 262144, 512, 512, 1, 0);
        poh = scr; pol = scr + 262144;
      }
      hipLaunchKernelGGL((gemm_bf<0, 0, 1, 0>), dim3(4, 32, 2), dim3(256), 0, stream,
                         ybh, ybl, poh, pol, bo + l * 512, nullptr, nullptr,
                         x, nullptr, nullptr, 4096, 512, 512, 256);
      hipLaunchKernelGGL(ln_pl, dim3(4096), dim3(256), 0, stream,
                         x, ln2_g + l * 512, ln2_b + l * 512, hh, hl);
      // MLP up + gelu, planes out
      const unsigned short *p1h, *p1l;
      if (bigws) { p1h = w1_h + (size_t)l * 1048576; p1l = w1_l + (size_t)l * 1048576; }
      else {
        CONV(W1 + (size_t)l * 1048576, scr, scr + 1048576, 512, 2048, 1, 0);
        p1h = scr; p1l = scr + 1048576;
      }
      hipLaunchKernelGGL((gemm_bf<1, 1, 0, 0>), dim3(16, 32, 1), dim3(256), 0, stream,
                         hh, hl, p1h, p1l, b1 + l * 2048, nullptr, nullptr,
                         nullptr, uh, ul, 4096, 2048, 512, 512);
      // MLP down: split-K=2, atomicAdd into x
      const unsigned short *p2h, *p2l;
      if (bigws) { p2h = w2_h + (size_t)l * 1048576; p2l = w2_l + (size_t)l * 1048576; }
      else {
        CONV(W2 + (size_t)l * 1048576, scr, scr + 1048576, 2048, 512, 1, 0);
        p2h = scr; p2l = scr + 1048576;
      }
      hipLaunchKernelGGL((gemm_bf<0, 0, 1, 0>), dim3(4, 32, 2), dim3(256), 0, stream,
                         uh, ul, p2h, p2l, b2 + l * 512, nullptr, nullptr,
                         x, nullptr, nullptr, 4096, 512, 2048, 1024);
    }
    hipLaunchKernelGGL(ln_pl, dim3(4096), dim3(256), 0, stream, x, lnf_g, lnf_b, hh, hl);
    // head projection (f32 + planes out) and decoder first layer (tanh)
    const unsigned short *pph, *ppl, *pdh, *pdl;
    if (bigws) { pph = wp_h; ppl = wp_l; }
    else { CONV(Wp, scr, scr + 131072, 512, 256, 1, 0); pph = scr; ppl = scr + 131072; }
    hipLaunchKernelGGL((gemm_bf<0, 2, 0, 0>), dim3(2, 32, 1), dim3(256), 0, stream,
                       hh, hl, pph, ppl, bp, nullptr, nullptr,
                       xo, xoh, xol, 4096, 256, 512, 512);
    if (bigws) { pdh = wd1_h; pdl = wd1_l; }
    else { CONV(Wd1, scr, scr + 65536, 256, 256, 1, 0); pdh = scr; pdl = scr + 65536; }
    hipLaunchKernelGGL((gemm_bf<2, 0, 0, 0>), dim3(2, 32, 1), dim3(256), 0, stream,
                       xoh, xol, pdh, pdl, bd1, nullptr, nullptr,
                       hd, nullptr, nullptr, 4096, 256, 256, 256);
    hipLaunchKernelGGL(ln_kernel, dim3(4096), dim3(256), 0, stream, hd, lnd_g, lnd_b, hd2, 256);
    G(0, hd2, Wd2, bd2, nullptr, pd, 4096, 64, 256);
    hipLaunchKernelGGL(loss_reg_kernel, dim3(256), dim3(256), 0, stream,
                       pd, tok, mask, lacc + (dir ? 1 : 0), dir);
    hipLaunchKernelGGL(frame_mean_kernel, dim3(512), dim3(256), 0, stream,
                       xo, xf, dir == 0 ? out_f : (float*)nullptr);
    G(2, xf, Wf1, bf1, nullptr, hf, 512, 256, 256);
    hipLaunchKernelGGL(ln_kernel, dim3(512), dim3(256), 0, stream, hf, lnfr_g, lnfr_b, hf2, 256);
    G(0, hf2, Wf2, bf2, nullptr, pf, 512, 512, 256);
    hipLaunchKernelGGL(loss_fr_kernel, dim3(256), dim3(256), 0, stream,
                       pf, tok, mask, lacc + (dir ? 3 : 2), dir);
  }
  hipLaunchKernelGGL(finalize_kernel, dim3(1), dim3(64), 0, stream, lacc, out_f);
}

// Round 6
// 2765.832 us; speedup vs baseline: 1.9591x; 1.9591x over previous
//
#include <hip/hip_runtime.h>
#include <math.h>

typedef short short8 __attribute__((ext_vector_type(8)));
typedef float f32x4 __attribute__((ext_vector_type(4)));

// ---------------- helpers ----------------
__device__ __forceinline__ float block_reduce(float v, float* red) {
  int tid = threadIdx.x;
  red[tid] = v; __syncthreads();
  for (int s = 128; s >= 1; s >>= 1) {
    if (tid < s) red[tid] += red[tid + s];
    __syncthreads();
  }
  float r = red[0];
  __syncthreads();
  return r;
}

// f32 -> (hi bf16, lo bf16). hi = round-half-up; lo = exact residual truncated.
__device__ __forceinline__ void cvt1(float x, unsigned short& h, unsigned short& l) {
  unsigned u = __float_as_uint(x);
  unsigned hb = (u + 0x8000u) & 0xffff0000u;
  h = (unsigned short)(hb >> 16);
  l = (unsigned short)(__float_as_uint(x - __uint_as_float(hb)) >> 16);
}

// pairwise-packed variant (elem a in low 16, b in high 16) — used by attention
__device__ __forceinline__ void cvt2(float a, float b, unsigned& hp, unsigned& lp) {
  unsigned ua = __float_as_uint(a), ub = __float_as_uint(b);
  unsigned ha = (ua + 0x8000u) & 0xffff0000u;
  unsigned hb = (ub + 0x8000u) & 0xffff0000u;
  float la = a - __uint_as_float(ha);
  float lb = b - __uint_as_float(hb);
  hp = (ha >> 16) | hb;
  lp = (__float_as_uint(la) >> 16) | (__float_as_uint(lb) & 0xffff0000u);
}

// async global -> LDS, 16B per lane. LDS dest: wave-uniform base + lane*16.
// Global src: per-lane (carries the swizzle). Drained by __syncthreads (vmcnt0).
__device__ __forceinline__ void gl2l(const unsigned short* g, unsigned short* l) {
  __builtin_amdgcn_global_load_lds(
      (const __attribute__((address_space(1))) void*)g,
      (__attribute__((address_space(3))) void*)l, 16, 0, 0);
}

union U8 { unsigned u[4]; short8 s; };

__global__ __launch_bounds__(256) void sentinel_kernel(float* __restrict__ out, int n, float v) {
  int i = blockIdx.x * 256 + threadIdx.x;
  if (i < n) out[i] = v;
}

// ---------------- BatchNorm stats ----------------
__global__ __launch_bounds__(256) void bn_stats_kernel(
    const float* __restrict__ tok, const float* __restrict__ g,
    const float* __restrict__ bb, float* __restrict__ ss) {
  __shared__ float red[256];
  const int d = blockIdx.x;
  float sum = 0.f, sumsq = 0.f;
  for (int s = threadIdx.x; s < 4096; s += 256) {
    float v = tok[s * 64 + d];
    sum += v; sumsq += v * v;
  }
  sum = block_reduce(sum, red);
  sumsq = block_reduce(sumsq, red);
  if (threadIdx.x == 0) {
    float mu = sum * (1.f / 4096.f);
    float var = sumsq * (1.f / 4096.f) - mu * mu;
    float sc = g[d] * rsqrtf(fmaxf(var, 0.f) + 1e-5f);
    ss[d] = sc;
    ss[64 + d] = bb[d] - mu * sc;
  }
}

__global__ __launch_bounds__(256) void tn_kernel(
    const float* __restrict__ tok, const float* __restrict__ ss,
    float* __restrict__ tn) {
  int idx = blockIdx.x * 256 + threadIdx.x;
  int d = idx & 63;
  tn[idx] = tok[idx] * ss[d] + ss[64 + d];
}

__global__ __launch_bounds__(256) void reverse_kernel(
    const float* __restrict__ x0, float* __restrict__ x0r) {
  int idx = blockIdx.x * 256 + threadIdx.x;
  int row = idx >> 9, e = idx & 511;
  int b = row >> 10, t = row & 1023;
  x0r[idx] = x0[((size_t)((b << 10) + (1023 - t))) * 512 + e];
}

// ---------------- row LayerNorm, f32 out (N = 512 or 256) ----------------
__global__ __launch_bounds__(256) void ln_kernel(
    const float* __restrict__ x, const float* __restrict__ g,
    const float* __restrict__ b, float* __restrict__ out, int N) {
  __shared__ float red[256];
  const size_t r = blockIdx.x;
  const int tid = threadIdx.x;
  float v0 = x[r * N + tid];
  float v1 = (N > 256) ? x[r * N + 256 + tid] : 0.f;
  float sum = block_reduce(v0 + v1, red);
  float sumsq = block_reduce(v0 * v0 + v1 * v1, red);
  float mean = sum / (float)N;
  float var = sumsq / (float)N - mean * mean;
  float rs = rsqrtf(fmaxf(var, 0.f) + 1e-5f);
  out[r * N + tid] = (v0 - mean) * rs * g[tid] + b[tid];
  if (N > 256)
    out[r * N + 256 + tid] = (v1 - mean) * rs * g[256 + tid] + b[256 + tid];
}

// ---------------- row LayerNorm, N=512, bf16 hi/lo plane out ----------------
__global__ __launch_bounds__(256) void ln_pl(
    const float* __restrict__ x, const float* __restrict__ g,
    const float* __restrict__ b, unsigned short* __restrict__ oh,
    unsigned short* __restrict__ ol) {
  __shared__ float red[256];
  const size_t r = blockIdx.x;
  const int tid = threadIdx.x;
  float v0 = x[r * 512 + tid];
  float v1 = x[r * 512 + 256 + tid];
  float sum = block_reduce(v0 + v1, red);
  float sumsq = block_reduce(v0 * v0 + v1 * v1, red);
  float mean = sum * (1.f / 512.f);
  float var = sumsq * (1.f / 512.f) - mean * mean;
  float rs = rsqrtf(fmaxf(var, 0.f) + 1e-5f);
  float o0 = (v0 - mean) * rs * g[tid] + b[tid];
  float o1 = (v1 - mean) * rs * g[256 + tid] + b[256 + tid];
  unsigned short h0, l0, h1, l1;
  cvt1(o0, h0, l0); cvt1(o1, h1, l1);
  oh[r * 512 + tid] = h0;       ol[r * 512 + tid] = l0;
  oh[r * 512 + 256 + tid] = h1; ol[r * 512 + 256 + tid] = l1;
}

// ---------------- weight conversion: f32 [K][N] -> transposed planes [N][K] ----------------
__global__ __launch_bounds__(256) void convw(
    const float* __restrict__ W, unsigned short* __restrict__ hi,
    unsigned short* __restrict__ lo, int K, int N, long dls) {
  int id = blockIdx.x * 256 + threadIdx.x;
  int total = (K >> 3) * N;
  if (id >= total) return;
  int c = id / N, n = id - c * N;
  const float* Wp = W + (size_t)blockIdx.y * K * N;
  size_t doff = (size_t)blockIdx.y * dls + (size_t)n * K + c * 8;
  unsigned short h8[8], l8[8];
#pragma unroll
  for (int j = 0; j < 8; ++j) {
    float xv = Wp[(size_t)(c * 8 + j) * N + n];
    cvt1(xv, h8[j], l8[j]);
  }
  uint4 hv = make_uint4(h8[0] | ((unsigned)h8[1] << 16), h8[2] | ((unsigned)h8[3] << 16),
                        h8[4] | ((unsigned)h8[5] << 16), h8[6] | ((unsigned)h8[7] << 16));
  uint4 lv = make_uint4(l8[0] | ((unsigned)l8[1] << 16), l8[2] | ((unsigned)l8[3] << 16),
                        l8[4] | ((unsigned)l8[5] << 16), l8[6] | ((unsigned)l8[7] << 16));
  *reinterpret_cast<uint4*>(hi + doff) = hv;
  *reinterpret_cast<uint4*>(lo + doff) = lv;
}

// --------- small GEMM (f32): out[M,N] = A@W + bias (act) ---------
#define BK 16
template <int ACT>  // 0 none, 1 gelu(exact), 2 tanh
__global__ __launch_bounds__(256) void gemm3(
    const float* __restrict__ A, const float* __restrict__ W,
    const float* __restrict__ bias, const float* resid,
    float* out, int M, int N, int K) {
  __shared__ float As[BK][64 + 4];
  __shared__ float Bs[BK][64 + 4];
  const int tid = threadIdx.x;
  const int tx = tid & 15, ty = tid >> 4;
  const int n0 = blockIdx.x * 64, m0 = blockIdx.y * 64;
  float acc[4][4] = {};
  for (int k0 = 0; k0 < K; k0 += BK) {
    {
      int m = tid >> 2, kq = tid & 3;
      float4 a4 = *reinterpret_cast<const float4*>(A + (size_t)(m0 + m) * K + k0 + kq * 4);
      As[kq * 4 + 0][m] = a4.x; As[kq * 4 + 1][m] = a4.y;
      As[kq * 4 + 2][m] = a4.z; As[kq * 4 + 3][m] = a4.w;
    }
    {
      int kk = tid >> 4, nq = tid & 15;
      float4 b4 = *reinterpret_cast<const float4*>(W + (size_t)(k0 + kk) * N + n0 + nq * 4);
      Bs[kk][nq * 4 + 0] = b4.x; Bs[kk][nq * 4 + 1] = b4.y;
      Bs[kk][nq * 4 + 2] = b4.z; Bs[kk][nq * 4 + 3] = b4.w;
    }
    __syncthreads();
#pragma unroll
    for (int kq = 0; kq < BK; ++kq) {
      float4 av = *reinterpret_cast<const float4*>(&As[kq][ty * 4]);
      float4 bv = *reinterpret_cast<const float4*>(&Bs[kq][tx * 4]);
      acc[0][0] += av.x * bv.x; acc[0][1] += av.x * bv.y; acc[0][2] += av.x * bv.z; acc[0][3] += av.x * bv.w;
      acc[1][0] += av.y * bv.x; acc[1][1] += av.y * bv.y; acc[1][2] += av.y * bv.z; acc[1][3] += av.y * bv.w;
      acc[2][0] += av.z * bv.x; acc[2][1] += av.z * bv.y; acc[2][2] += av.z * bv.z; acc[2][3] += av.z * bv.w;
      acc[3][0] += av.w * bv.x; acc[3][1] += av.w * bv.y; acc[3][2] += av.w * bv.z; acc[3][3] += av.w * bv.w;
    }
    __syncthreads();
  }
#pragma unroll
  for (int i = 0; i < 4; ++i) {
    int m = m0 + ty * 4 + i;
#pragma unroll
    for (int j = 0; j < 4; ++j) {
      int n = n0 + tx * 4 + j;
      float v = acc[i][j] + bias[n];
      if (resid) v += resid[(size_t)m * N + n];
      if (ACT == 1) v = 0.5f * v * (1.f + erff(v * 0.70710678118654752f));
      if (ACT == 2) v = tanhf(v);
      out[(size_t)m * N + n] = v;
    }
  }
}

// --------- MFMA GEMM over pre-split bf16 planes. 128x128x32 tiles, 4 waves. ---------
// Staging via global_load_lds (16B/lane) into double-buffered LDS; one barrier per
// K-step drains the prefetch (vmcnt0 in __syncthreads). Wave w owns plane w
// (0=Ah 1=Al 2=Bh 3=Bl): 8 x 1KB chunks per K-step. The XOR slot swizzle
// (slot ^ (row>>1)&3) is applied on the per-lane GLOBAL address; LDS stays linear,
// fragment ds_read_b128 reads are conflict-free (measured 0 in r5).
// ACT: 0 none, 1 gelu, 2 tanh. OUTMODE: 0 f32, 1 planes, 2 both.
// ATOMIC: f32 atomicAdd into Cf (bias added by z==0). BIAS3: b0/b1/b2 512-wide sections.
template <int ACT, int OUTMODE, int ATOMIC, int BIAS3>
__global__ __launch_bounds__(256, 2) void gemm_bf(
    const unsigned short* __restrict__ Ahp, const unsigned short* __restrict__ Alp,
    const unsigned short* __restrict__ Bhp, const unsigned short* __restrict__ Blp,
    const float* __restrict__ b0, const float* __restrict__ b1, const float* __restrict__ b2,
    float* __restrict__ Cf, unsigned short* __restrict__ Chp, unsigned short* __restrict__ Clp,
    int M, int N, int K, int KZ) {
  // [buf][plane][row][32 ushorts]: 2 x 32KB
  __shared__ __align__(16) unsigned short LDS[2][4][128][32];
  const int tid = threadIdx.x;
  const int lane = tid & 63, wid = tid >> 6;
  const int wr = wid >> 1, wc = wid & 1;
  const int lr = lane & 15, lq = lane >> 4;

  // XCD swizzle over (x,y)
  const int gx = gridDim.x;
  int lin = blockIdx.y * gx + blockIdx.x;
  int qch = (gx * gridDim.y) >> 3;
  int swz = (lin & 7) * qch + (lin >> 3);
  const int nb = swz % gx, mb = swz / gx;
  const int n0 = nb * 128, m0 = mb * 128;
  const int kbase = blockIdx.z * KZ, kend = kbase + KZ;

  f32x4 acc[4][4];
#pragma unroll
  for (int i = 0; i < 4; ++i)
#pragma unroll
    for (int j = 0; j < 4; ++j) { acc[i][j][0] = 0.f; acc[i][j][1] = 0.f; acc[i][j][2] = 0.f; acc[i][j][3] = 0.f; }

  // wave wid stages plane wid
  const unsigned short* gplane =
      (wid == 0) ? Ahp + (size_t)m0 * K :
      (wid == 1) ? Alp + (size_t)m0 * K :
      (wid == 2) ? Bhp + (size_t)n0 * K : Blp + (size_t)n0 * K;
  const int srow = lane >> 2;   // 0..15 within a 16-row chunk
  const int sphys = lane & 3;   // physical 16B slot

  auto stage = [&](int buf, int k0) {
#pragma unroll
    for (int j = 0; j < 8; ++j) {
      int row = j * 16 + srow;
      int logslot = sphys ^ ((row >> 1) & 3);
      gl2l(gplane + (size_t)row * K + k0 + logslot * 8, &LDS[buf][wid][j * 16][0]);
    }
  };

  stage(0, kbase);
  __syncthreads();
  int cur = 0;
  for (int k0 = kbase; k0 < kend; k0 += 32) {
    if (k0 + 32 < kend) stage(cur ^ 1, k0 + 32);
    short8 ah[4], al[4], bh[4], bl[4];
#pragma unroll
    for (int mi = 0; mi < 4; ++mi) {
      int row = wr * 64 + mi * 16 + lr;
      int off = (lq ^ ((row >> 1) & 3)) * 8;
      ah[mi] = *reinterpret_cast<const short8*>(&LDS[cur][0][row][off]);
      al[mi] = *reinterpret_cast<const short8*>(&LDS[cur][1][row][off]);
    }
#pragma unroll
    for (int ni = 0; ni < 4; ++ni) {
      int n = wc * 64 + ni * 16 + lr;
      int off = (lq ^ ((n >> 1) & 3)) * 8;
      bh[ni] = *reinterpret_cast<const short8*>(&LDS[cur][2][n][off]);
      bl[ni] = *reinterpret_cast<const short8*>(&LDS[cur][3][n][off]);
    }
#pragma unroll
    for (int mi = 0; mi < 4; ++mi)
#pragma unroll
      for (int ni = 0; ni < 4; ++ni) {
        acc[mi][ni] = __builtin_amdgcn_mfma_f32_16x16x32_bf16(ah[mi], bh[ni], acc[mi][ni], 0, 0, 0);
        acc[mi][ni] = __builtin_amdgcn_mfma_f32_16x16x32_bf16(ah[mi], bl[ni], acc[mi][ni], 0, 0, 0);
        acc[mi][ni] = __builtin_amdgcn_mfma_f32_16x16x32_bf16(al[mi], bh[ni], acc[mi][ni], 0, 0, 0);
      }
    __syncthreads();   // drains prefetch (vmcnt0) + frees cur for next stage
    cur ^= 1;
  }

  // ---- epilogue ----
  const float* bsec = b0;
  int bof = 0;
  if (BIAS3) { bsec = (n0 < 512) ? b0 : (n0 < 1024 ? b1 : b2); bof = (n0 & 511) - n0; }
#pragma unroll
  for (int mi = 0; mi < 4; ++mi) {
#pragma unroll
    for (int r = 0; r < 4; ++r) {
      int grow = m0 + wr * 64 + mi * 16 + lq * 4 + r;
#pragma unroll
      for (int ni = 0; ni < 4; ++ni) {
        int col = n0 + wc * 64 + ni * 16 + lr;
        float v = acc[mi][ni][r];
        float bias = BIAS3 ? bsec[col + bof] : b0[col];
        if (ATOMIC) {
          if (blockIdx.z == 0) v += bias;
          atomicAdd(&Cf[(size_t)grow * N + col], v);
        } else {
          v += bias;
          if (ACT == 1) v = 0.5f * v * (1.f + erff(v * 0.70710678118654752f));
          if (ACT == 2) v = tanhf(v);
          if (OUTMODE == 0 || OUTMODE == 2) Cf[(size_t)grow * N + col] = v;
          if (OUTMODE >= 1) {
            unsigned short hv, lv;
            cvt1(v, hv, lv);
            Chp[(size_t)grow * N + col] = hv;
            Clp[(size_t)grow * N + col] = lv;
          }
        }
      }
    }
  }
}

// ---------------- attention: MFMA flash, bf16x3, 64x64 tiles ----------------
// Reads fused qkv f32 buffer [4096][1536] (q|k|v); writes yb as bf16 hi/lo planes.
__global__ __launch_bounds__(256, 2) void attn_mfma(
    const float* __restrict__ qkv, const float* __restrict__ mask,
    unsigned short* __restrict__ ybh, unsigned short* __restrict__ ybl, int rev) {
  __shared__ __align__(16) unsigned SH[4096];       // 16KB: Q staging, then V^T hi/lo
  __shared__ __align__(16) unsigned KhL[2048];      // 8KB  K hi
  __shared__ __align__(16) unsigned KlL[2048];      // 8KB  K lo
  __shared__ float PU[64 * 68];                     // 17KB P (f32)
  __shared__ float km[64];
  unsigned* VhL = SH;
  unsigned* VlL = SH + 2048;

  const int tid = threadIdx.x;
  const int lane = tid & 63, w = tid >> 6;
  const int lr = lane & 15, lq = lane >> 4;

  const int id = blockIdx.x;          // complementary-pair mapping
  const int top = id >> 8;
  const int r5 = id & 255;
  const int qt = top ? (15 - (r5 >> 4)) : (r5 >> 4);
  const int bh_ = (r5 & 15) | (top << 4);
  const int b = bh_ >> 3, h = bh_ & 7;

  // ---- stage Q (scaled 1/8) into SH, swizzled ----
  {
    const float* qp = qkv + (size_t)(b * 1024 + qt * 64) * 1536 + h * 64;
    int row = tid >> 2, f4 = tid & 3;
#pragma unroll
    for (int j = 0; j < 4; ++j) {
      int dk = f4 * 4 + j * 16;
      float4 a = *reinterpret_cast<const float4*>(qp + (size_t)row * 1536 + dk);
      unsigned h0, l0, h1, l1;
      cvt2(a.x * 0.125f, a.y * 0.125f, h0, l0);
      cvt2(a.z * 0.125f, a.w * 0.125f, h1, l1);
      int phys = (dk >> 3) ^ (row & 7);
      int off = row * 32 + phys * 4 + (f4 & 1) * 2;
      *reinterpret_cast<uint2*>(&SH[off]) = make_uint2(h0, h1);
      *reinterpret_cast<uint2*>(&KhL[off]) = make_uint2(l0, l1);  // temp: Q-lo in KhL
    }
  }
  __syncthreads();
  short8 qa_h[2], qa_l[2];
#pragma unroll
  for (int ks = 0; ks < 2; ++ks) {
    int row = w * 16 + lr;
    int phys = (lq + ks * 4) ^ (row & 7);
    qa_h[ks] = *reinterpret_cast<const short8*>(&SH[row * 32 + phys * 4]);
    qa_l[ks] = *reinterpret_cast<const short8*>(&KhL[row * 32 + phys * 4]);
  }
  __syncthreads();  // SH/KhL now free for V^T / K tiles

  float m_[4], l_[4] = {0.f, 0.f, 0.f, 0.f};
  f32x4 o_[4];
#pragma unroll
  for (int r = 0; r < 4; ++r) m_[r] = -1e30f;
#pragma unroll
  for (int df = 0; df < 4; ++df) { o_[df][0] = 0.f; o_[df][1] = 0.f; o_[df][2] = 0.f; o_[df][3] = 0.f; }

  for (int kt = 0; kt <= qt; ++kt) {
    const float* kp = qkv + (size_t)(b * 1024 + kt * 64) * 1536 + 512 + h * 64;
    const float* vp = qkv + (size_t)(b * 1024 + kt * 64) * 1536 + 1024 + h * 64;
    // ---- stage K (row-major, swizzled) ----
    {
      int row = tid >> 2, f4 = tid & 3;
#pragma unroll
      for (int j = 0; j < 4; ++j) {
        int dk = f4 * 4 + j * 16;
        float4 a = *reinterpret_cast<const float4*>(kp + (size_t)row * 1536 + dk);
        unsigned h0, l0, h1, l1;
        cvt2(a.x, a.y, h0, l0);
        cvt2(a.z, a.w, h1, l1);
        int phys = (dk >> 3) ^ (row & 7);
        int off = row * 32 + phys * 4 + (f4 & 1) * 2;
        *reinterpret_cast<uint2*>(&KhL[off]) = make_uint2(h0, h1);
        *reinterpret_cast<uint2*>(&KlL[off]) = make_uint2(l0, l1);
      }
    }
    // ---- stage V^T (key-pairs packed per uint, swizzled) ----
    {
      int d = tid & 63, g = tid >> 6;
#pragma unroll
      for (int j = 0; j < 8; ++j) {
        int kpair = (g + j * 4 + (d >> 3)) & 31;
        float v0 = vp[(size_t)(kpair * 2) * 1536 + d];
        float v1 = vp[(size_t)(kpair * 2 + 1) * 1536 + d];
        unsigned hh, ll;
        cvt2(v0, v1, hh, ll);
        int phys = (kpair >> 2) ^ (d & 7);
        int off = d * 32 + phys * 4 + (kpair & 3);
        VhL[off] = hh; VlL[off] = ll;
      }
    }
    if (tid < 64) {
      int s = kt * 64 + tid;
      km[tid] = mask[b * 1024 + (rev ? (1023 - s) : s)];
    }
    __syncthreads();

    // ---- S = Q K^T (x3 MFMA) ----
    f32x4 sacc[4];
#pragma unroll
    for (int kf = 0; kf < 4; ++kf) { sacc[kf][0] = 0.f; sacc[kf][1] = 0.f; sacc[kf][2] = 0.f; sacc[kf][3] = 0.f; }
#pragma unroll
    for (int ks = 0; ks < 2; ++ks) {
#pragma unroll
      for (int kf = 0; kf < 4; ++kf) {
        int col = kf * 16 + lr;
        int phys = (lq + ks * 4) ^ (lr & 7);
        short8 kbh = *reinterpret_cast<const short8*>(&KhL[col * 32 + phys * 4]);
        short8 kbl = *reinterpret_cast<const short8*>(&KlL[col * 32 + phys * 4]);
        sacc[kf] = __builtin_amdgcn_mfma_f32_16x16x32_bf16(qa_h[ks], kbh, sacc[kf], 0, 0, 0);
        sacc[kf] = __builtin_amdgcn_mfma_f32_16x16x32_bf16(qa_h[ks], kbl, sacc[kf], 0, 0, 0);
        sacc[kf] = __builtin_amdgcn_mfma_f32_16x16x32_bf16(qa_l[ks], kbh, sacc[kf], 0, 0, 0);
      }
    }

    // ---- online softmax in registers ----
    const bool diag = (kt == qt);
    float kmv[4];
#pragma unroll
    for (int kf = 0; kf < 4; ++kf) kmv[kf] = km[kf * 16 + lr];
#pragma unroll
    for (int r = 0; r < 4; ++r) {
      int fi = (w * 16 + lq * 4 + r) >> 3;
      float mt = -1e30f;
#pragma unroll
      for (int kf = 0; kf < 4; ++kf) {
        int key = kf * 16 + lr;
        bool ok = (kmv[kf] > 0.f) && (!diag || ((key >> 3) <= fi));
        float x = ok ? sacc[kf][r] : -1e30f;
        sacc[kf][r] = x;
        mt = fmaxf(mt, x);
      }
      mt = fmaxf(mt, __shfl_xor(mt, 1, 16));
      mt = fmaxf(mt, __shfl_xor(mt, 2, 16));
      mt = fmaxf(mt, __shfl_xor(mt, 4, 16));
      mt = fmaxf(mt, __shfl_xor(mt, 8, 16));
      float mn = fmaxf(m_[r], mt);
      float al = __expf(m_[r] - mn);
      m_[r] = mn;
      float rs = 0.f;
#pragma unroll
      for (int kf = 0; kf < 4; ++kf) {
        float sv = sacc[kf][r];
        float p = (sv > -1e29f) ? __expf(sv - mn) : 0.f;
        sacc[kf][r] = p;
        rs += p;
      }
      rs += __shfl_xor(rs, 1, 16);
      rs += __shfl_xor(rs, 2, 16);
      rs += __shfl_xor(rs, 4, 16);
      rs += __shfl_xor(rs, 8, 16);
      l_[r] = l_[r] * al + rs;
#pragma unroll
      for (int df = 0; df < 4; ++df) o_[df][r] *= al;
    }
    // ---- write P (f32, 68-stride) ----
#pragma unroll
    for (int kf = 0; kf < 4; ++kf)
#pragma unroll
      for (int r = 0; r < 4; ++r)
        PU[(w * 16 + lq * 4 + r) * 68 + kf * 16 + lr] = sacc[kf][r];
    __syncthreads();

    // ---- O += P V (x3 MFMA) ----
#pragma unroll
    for (int ks = 0; ks < 2; ++ks) {
      const float* pp = &PU[(w * 16 + lr) * 68 + ks * 32 + lq * 8];
      float4 p0 = *reinterpret_cast<const float4*>(pp);
      float4 p1 = *reinterpret_cast<const float4*>(pp + 4);
      U8 th, tl;
      cvt2(p0.x, p0.y, th.u[0], tl.u[0]);
      cvt2(p0.z, p0.w, th.u[1], tl.u[1]);
      cvt2(p1.x, p1.y, th.u[2], tl.u[2]);
      cvt2(p1.z, p1.w, th.u[3], tl.u[3]);
      short8 pa_h = th.s, pa_l = tl.s;
#pragma unroll
      for (int df = 0; df < 4; ++df) {
        int col = df * 16 + lr;
        int phys = (lq + ks * 4) ^ (lr & 7);
        short8 vbh = *reinterpret_cast<const short8*>(&VhL[col * 32 + phys * 4]);
        short8 vbl = *reinterpret_cast<const short8*>(&VlL[col * 32 + phys * 4]);
        o_[df] = __builtin_amdgcn_mfma_f32_16x16x32_bf16(pa_h, vbh, o_[df], 0, 0, 0);
        o_[df] = __builtin_amdgcn_mfma_f32_16x16x32_bf16(pa_h, vbl, o_[df], 0, 0, 0);
        o_[df] = __builtin_amdgcn_mfma_f32_16x16x32_bf16(pa_l, vbh, o_[df], 0, 0, 0);
      }
    }
    __syncthreads();
  }

  // ---- normalize + write planes ----
#pragma unroll
  for (int r = 0; r < 4; ++r) {
    float inv = 1.f / fmaxf(l_[r], 1e-30f);
    int qrow = qt * 64 + w * 16 + lq * 4 + r;
#pragma unroll
    for (int df = 0; df < 4; ++df) {
      float val = o_[df][r] * inv;
      unsigned short hv, lv;
      cvt1(val, hv, lv);
      size_t idx = (size_t)(b * 1024 + qrow) * 512 + h * 64 + df * 16 + lr;
      ybh[idx] = hv; ybl[idx] = lv;
    }
  }
}

// ---------------- frame mean (+ FLOAT32 output write) ----------------
__global__ __launch_bounds__(256) void frame_mean_kernel(
    const float* __restrict__ xo, float* __restrict__ xf,
    float* __restrict__ outf) {
  int row = blockIdx.x;       // b*128+tf
  int o = threadIdx.x;
  float s = 0.f;
#pragma unroll
  for (int c = 0; c < 8; ++c) s += xo[((size_t)row * 8 + c) * 256 + o];
  s *= 0.125f;
  xf[row * 256 + o] = s;
  if (outf) outf[row * 256 + o] = s;
}

// ---------------- losses ----------------
__global__ __launch_bounds__(256) void loss_reg_kernel(
    const float* __restrict__ pd, const float* __restrict__ tok,
    const float* __restrict__ mask, float* __restrict__ acc, int rev) {
  __shared__ float red[256];
  float local = 0.f;
  for (int idx = blockIdx.x * 256 + threadIdx.x; idx < 260096; idx += gridDim.x * 256) {
    int b = idx / 65024, r2 = idx % 65024;
    int t = r2 >> 6, d = r2 & 63;
    float pred = pd[((size_t)((b << 10) + t)) * 64 + d] * mask[(b << 10) + t];
    int tt = rev ? (1015 - t) : (t + 8);
    float tgt = tok[((size_t)((b << 10) + tt)) * 64 + d] * mask[(b << 10) + tt];
    float df = pred - tgt;
    local += df * df;
  }
  float s = block_reduce(local, red);
  if (threadIdx.x == 0) atomicAdd(acc, s);
}

__global__ __launch_bounds__(256) void loss_fr_kernel(
    const float* __restrict__ pf, const float* __restrict__ tok,
    const float* __restrict__ mask, float* __restrict__ acc, int rev) {
  __shared__ float red[256];
  float local = 0.f;
  for (int idx = blockIdx.x * 256 + threadIdx.x; idx < 260096; idx += gridDim.x * 256) {
    int b = idx / 65024, r2 = idx % 65024;
    int i = r2 >> 9, u = r2 & 511;
    float pred = pf[((size_t)(b * 128 + i)) * 512 + u];
    int c = u >> 6;
    int t = rev ? ((126 - i) * 8 + c) : ((i + 1) * 8 + c);
    float tgt = tok[((size_t)((b << 10) + t)) * 64 + (u & 63)] * mask[(b << 10) + t];
    float df = pred - tgt;
    local += df * df;
  }
  float s = block_reduce(local, red);
  if (threadIdx.x == 0) atomicAdd(acc, s);
}

__global__ void finalize_kernel(const float* __restrict__ acc, float* __restrict__ out) {
  int i = threadIdx.x;
  if (i < 4) out[131072 + i] = acc[i] * (1.0f / 260096.0f);
}

extern "C" void kernel_launch(void* const* d_in, const int* in_sizes, int n_in,
                              void* d_out, int out_size, void* d_ws, size_t ws_size,
                              hipStream_t stream) {
  float* ws = (float*)d_ws;
  const size_t OFF_SS   = 0;
  const size_t OFF_LACC = 128;
  const size_t OFF_TN   = 256;
  const size_t OFF_X0   = 262400;
  const size_t OFF_X0R  = 2359552;
  const size_t OFF_X    = 4456704;
  const size_t OFF_HPL  = 6553856;    // h planes (hi 1048576 fl, lo 1048576 fl)
  const size_t OFF_QKV  = 8651008;    // qkv f32 6291456 fl; u planes alias
  const size_t OFF_YB   = 14942464;   // yb planes 2097152 fl
  const size_t OFF_XO   = 17039616;   // f32 1048576
  const size_t OFF_XOPL = 18088192;   // xo planes 1048576 fl
  const size_t OFF_HD   = 19136768;
  const size_t OFF_HD2  = 20185344;
  const size_t OFF_PD   = 21233920;
  const size_t OFF_XF   = 21496064;
  const size_t OFF_HF   = 21627136;
  const size_t OFF_HF2  = 21758208;
  const size_t OFF_PF   = 21889280;
  const size_t OFF_WB   = 22151424;
  const size_t TOTAL_MIN = OFF_WB + 1048576;    // JIT scratch mode (~92.8 MB)
  const size_t TOTAL_BIG = OFF_WB + 19070976;   // full weight-plane mode (~165 MB)

  float* ss   = ws + OFF_SS;
  float* lacc = ws + OFF_LACC;
  float* tn   = ws + OFF_TN;
  float* x0   = ws + OFF_X0;
  float* x0r  = ws + OFF_X0R;
  float* x    = ws + OFF_X;
  unsigned short* hh = (unsigned short*)(ws + OFF_HPL);
  unsigned short* hl = hh + 2097152;
  float* qkv  = ws + OFF_QKV;
  unsigned short* uh = (unsigned short*)(ws + OFF_QKV);   // alias (MLP phase only)
  unsigned short* ul = uh + 8388608;
  unsigned short* ybh = (unsigned short*)(ws + OFF_YB);
  unsigned short* ybl = ybh + 2097152;
  float* xo   = ws + OFF_XO;
  unsigned short* xoh = (unsigned short*)(ws + OFF_XOPL);
  unsigned short* xol = xoh + 1048576;
  float* hd   = ws + OFF_HD;
  float* hd2  = ws + OFF_HD2;
  float* pd   = ws + OFF_PD;
  float* xf   = ws + OFF_XF;
  float* hf   = ws + OFF_HF;
  float* hf2  = ws + OFF_HF2;
  float* pf   = ws + OFF_PF;
  unsigned short* wb16 = (unsigned short*)(ws + OFF_WB);
  float* out_f = (float*)d_out;   // OUTPUT IS FLOAT32

  static const int EXPECTED[39] = {
      262144, 4096, 4096, 64, 64, 32768, 512, 3072, 3072, 3072, 3072,
      1572864, 3072, 1572864, 3072, 1572864, 3072, 1572864, 3072,
      6291456, 12288, 6291456, 3072, 512, 512, 131072, 256, 65536, 256,
      256, 256, 16384, 64, 65536, 256, 256, 256, 131072, 512};
  bool manifest_ok = (n_in == 39) && (ws_size >= TOTAL_MIN * sizeof(float));
  if (manifest_ok)
    for (int i = 0; i < 39; ++i)
      if (in_sizes[i] != EXPECTED[i]) { manifest_ok = false; break; }
  if (!manifest_ok) {
    hipLaunchKernelGGL(sentinel_kernel, dim3((out_size + 255) / 256), dim3(256), 0, stream,
                       out_f, out_size, 2000.0f);
    return;
  }
  const bool bigws = ws_size >= TOTAL_BIG * sizeof(float);

  const float* tok    = (const float*)d_in[0];
  const float* mask   = (const float*)d_in[2];
  const float* bn_g   = (const float*)d_in[3];
  const float* bn_b   = (const float*)d_in[4];
  const float* We     = (const float*)d_in[5];
  const float* be     = (const float*)d_in[6];
  const float* ln1_g  = (const float*)d_in[7];
  const float* ln1_b  = (const float*)d_in[8];
  const float* ln2_g  = (const float*)d_in[9];
  const float* ln2_b  = (const float*)d_in[10];
  const float* Wq     = (const float*)d_in[11];
  const float* bq     = (const float*)d_in[12];
  const float* Wk     = (const float*)d_in[13];
  const float* bk     = (const float*)d_in[14];
  const float* Wv     = (const float*)d_in[15];
  const float* bv     = (const float*)d_in[16];
  const float* Wo     = (const float*)d_in[17];
  const float* bo     = (const float*)d_in[18];
  const float* W1     = (const float*)d_in[19];
  const float* b1     = (const float*)d_in[20];
  const float* W2     = (const float*)d_in[21];
  const float* b2     = (const float*)d_in[22];
  const float* lnf_g  = (const float*)d_in[23];
  const float* lnf_b  = (const float*)d_in[24];
  const float* Wp     = (const float*)d_in[25];
  const float* bp     = (const float*)d_in[26];
  const float* Wd1    = (const float*)d_in[27];
  const float* bd1    = (const float*)d_in[28];
  const float* lnd_g  = (const float*)d_in[29];
  const float* lnd_b  = (const float*)d_in[30];
  const float* Wd2    = (const float*)d_in[31];
  const float* bd2    = (const float*)d_in[32];
  const float* Wf1    = (const float*)d_in[33];
  const float* bf1    = (const float*)d_in[34];
  const float* lnfr_g = (const float*)d_in[35];
  const float* lnfr_b = (const float*)d_in[36];
  const float* Wf2    = (const float*)d_in[37];
  const float* bf2    = (const float*)d_in[38];

  // weight-plane pointers (big mode), ushort offsets
  unsigned short* wqkv_h = wb16;
  unsigned short* wqkv_l = wb16 + 4718592;
  unsigned short* wo_h   = wb16 + 9437184;
  unsigned short* wo_l   = wb16 + 11010048;
  unsigned short* w1_h   = wb16 + 12582912;
  unsigned short* w1_l   = wb16 + 18874368;
  unsigned short* w2_h   = wb16 + 25165824;
  unsigned short* w2_l   = wb16 + 31457280;
  unsigned short* wp_h   = wb16 + 37748736;
  unsigned short* wp_l   = wb16 + 37879808;
  unsigned short* wd1_h  = wb16 + 38010880;
  unsigned short* wd1_l  = wb16 + 38076416;
  unsigned short* scr    = wb16;   // JIT scratch (small mode)

  auto G = [&](int act, const float* A, const float* W, const float* bias,
               const float* resid, float* out, int M, int N, int K) {
    dim3 g(N / 64, M / 64), b(256);
    if (act == 0) hipLaunchKernelGGL((gemm3<0>), g, b, 0, stream, A, W, bias, resid, out, M, N, K);
    else if (act == 1) hipLaunchKernelGGL((gemm3<1>), g, b, 0, stream, A, W, bias, resid, out, M, N, K);
    else hipLaunchKernelGGL((gemm3<2>), g, b, 0, stream, A, W, bias, resid, out, M, N, K);
  };
  auto CONV = [&](const float* W, unsigned short* hi, unsigned short* lo,
                  int K, int N, int layers, long dls) {
    int blocks = ((K >> 3) * N + 255) / 256;
    hipLaunchKernelGGL(convw, dim3(blocks, layers), dim3(256), 0, stream, W, hi, lo, K, N, dls);
  };

  hipMemsetAsync(lacc, 0, 4 * sizeof(float), stream);
  if (bigws) {  // one-time full weight conversion
    CONV(Wq, wqkv_h,          wqkv_l,          512, 512, 6, 786432);
    CONV(Wk, wqkv_h + 262144, wqkv_l + 262144, 512, 512, 6, 786432);
    CONV(Wv, wqkv_h + 524288, wqkv_l + 524288, 512, 512, 6, 786432);
    CONV(Wo, wo_h, wo_l, 512, 512, 6, 262144);
    CONV(W1, w1_h, w1_l, 512, 2048, 6, 1048576);
    CONV(W2, w2_h, w2_l, 2048, 512, 6, 1048576);
    CONV(Wp, wp_h, wp_l, 512, 256, 1, 0);
    CONV(Wd1, wd1_h, wd1_l, 256, 256, 1, 0);
  }
  hipLaunchKernelGGL(bn_stats_kernel, dim3(64), dim3(256), 0, stream, tok, bn_g, bn_b, ss);
  hipLaunchKernelGGL(tn_kernel, dim3(1024), dim3(256), 0, stream, tok, ss, tn);
  G(0, tn, We, be, nullptr, x0, 4096, 512, 64);
  hipLaunchKernelGGL(reverse_kernel, dim3(8192), dim3(256), 0, stream, x0, x0r);

  for (int dir = 0; dir < 2; ++dir) {
    const float* xin = dir ? x0r : x0;
    for (int l = 0; l < 6; ++l) {
      const float* xl = (l == 0) ? xin : x;
      hipLaunchKernelGGL(ln_pl, dim3(4096), dim3(256), 0, stream,
                         xl, ln1_g + l * 512, ln1_b + l * 512, hh, hl);
      // fused QKV GEMM, N=1536
      const unsigned short *pqh, *pql;
      if (bigws) { pqh = wqkv_h + (size_t)l * 786432; pql = wqkv_l + (size_t)l * 786432; }
      else {
        CONV(Wq + (size_t)l * 262144, scr,          scr + 786432,          512, 512, 1, 0);
        CONV(Wk + (size_t)l * 262144, scr + 262144, scr + 786432 + 262144, 512, 512, 1, 0);
        CONV(Wv + (size_t)l * 262144, scr + 524288, scr + 786432 + 524288, 512, 512, 1, 0);
        pqh = scr; pql = scr + 786432;
      }
      hipLaunchKernelGGL((gemm_bf<0, 0, 0, 1>), dim3(12, 32, 1), dim3(256), 0, stream,
                         hh, hl, pqh, pql, bq + l * 512, bk + l * 512, bv + l * 512,
                         qkv, nullptr, nullptr, 4096, 1536, 512, 512);
      // seed x with the residual for layer 0
      if (l == 0)
        hipMemcpyAsync(x, xin, 2097152 * sizeof(float), hipMemcpyDeviceToDevice, stream);
      hipLaunchKernelGGL(attn_mfma, dim3(512), dim3(256), 0, stream, qkv, mask, ybh, ybl, dir);
      // O-proj: split-K=2, atomicAdd into x (x pre-holds residual)
      const unsigned short *poh, *pol;
      if (bigws) { poh = wo_h + (size_t)l * 262144; pol = wo_l + (size_t)l * 262144; }
      else {
        CONV(Wo + (size_t)l * 262144, scr, scr + 262144, 512, 512, 1, 0);
        poh = scr; pol = scr + 262144;
      }
      hipLaunchKernelGGL((gemm_bf<0, 0, 1, 0>), dim3(4, 32, 2), dim3(256), 0, stream,
                         ybh, ybl, poh, pol, bo + l * 512, nullptr, nullptr,
                         x, nullptr, nullptr, 4096, 512, 512, 256);
      hipLaunchKernelGGL(ln_pl, dim3(4096), dim3(256), 0, stream,
                         x, ln2_g + l * 512, ln2_b + l * 512, hh, hl);
      // MLP up + gelu, planes out
      const unsigned short *p1h, *p1l;
      if (bigws) { p1h = w1_h + (size_t)l * 1048576; p1l = w1_l + (size_t)l * 1048576; }
      else {
        CONV(W1 + (size_t)l * 1048576, scr, scr + 1048576, 512, 2048, 1, 0);
        p1h = scr; p1l = scr + 1048576;
      }
      hipLaunchKernelGGL((gemm_bf<1, 1, 0, 0>), dim3(16, 32, 1), dim3(256), 0, stream,
                         hh, hl, p1h, p1l, b1 + l * 2048, nullptr, nullptr,
                         nullptr, uh, ul, 4096, 2048, 512, 512);
      // MLP down: split-K=2, atomicAdd into x
      const unsigned short *p2h, *p2l;
      if (bigws) { p2h = w2_h + (size_t)l * 1048576; p2l = w2_l + (size_t)l * 1048576; }
      else {
        CONV(W2 + (size_t)l * 1048576, scr, scr + 1048576, 2048, 512, 1, 0);
        p2h = scr; p2l = scr + 1048576;
      }
      hipLaunchKernelGGL((gemm_bf<0, 0, 1, 0>), dim3(4, 32, 2), dim3(256), 0, stream,
                         uh, ul, p2h, p2l, b2 + l * 512, nullptr, nullptr,
                         x, nullptr, nullptr, 4096, 512, 2048, 1024);
    }
    hipLaunchKernelGGL(ln_pl, dim3(4096), dim3(256), 0, stream, x, lnf_g, lnf_b, hh, hl);
    // head projection (f32 + planes out) and decoder first layer (tanh)
    const unsigned short *pph, *ppl, *pdh, *pdl;
    if (bigws) { pph = wp_h; ppl = wp_l; }
    else { CONV(Wp, scr, scr + 131072, 512, 256, 1, 0); pph = scr; ppl = scr + 131072; }
    hipLaunchKernelGGL((gemm_bf<0, 2, 0, 0>), dim3(2, 32, 1), dim3(256), 0, stream,
                       hh, hl, pph, ppl, bp, nullptr, nullptr,
                       xo, xoh, xol, 4096, 256, 512, 512);
    if (bigws) { pdh = wd1_h; pdl = wd1_l; }
    else { CONV(Wd1, scr, scr + 65536, 256, 256, 1, 0); pdh = scr; pdl = scr + 65536; }
    hipLaunchKernelGGL((gemm_bf<2, 0, 0, 0>), dim3(2, 32, 1), dim3(256), 0, stream,
                       xoh, xol, pdh, pdl, bd1, nullptr, nullptr,
                       hd, nullptr, nullptr, 4096, 256, 256, 256);
    hipLaunchKernelGGL(ln_kernel, dim3(4096), dim3(256), 0, stream, hd, lnd_g, lnd_b, hd2, 256);
    G(0, hd2, Wd2, bd2, nullptr, pd, 4096, 64, 256);
    hipLaunchKernelGGL(loss_reg_kernel, dim3(256), dim3(256), 0, stream,
                       pd, tok, mask, lacc + (dir ? 1 : 0), dir);
    hipLaunchKernelGGL(frame_mean_kernel, dim3(512), dim3(256), 0, stream,
                       xo, xf, dir == 0 ? out_f : (float*)nullptr);
    G(2, xf, Wf1, bf1, nullptr, hf, 512, 256, 256);
    hipLaunchKernelGGL(ln_kernel, dim3(512), dim3(256), 0, stream, hf, lnfr_g, lnfr_b, hf2, 256);
    G(0, hf2, Wf2, bf2, nullptr, pf, 512, 512, 256);
    hipLaunchKernelGGL(loss_fr_kernel, dim3(256), dim3(256), 0, stream,
                       pf, tok, mask, lacc + (dir ? 3 : 2), dir);
  }
  hipLaunchKernelGGL(finalize_kernel, dim3(1), dim3(64), 0, stream, lacc, out_f);
}

// Round 7
// 2732.519 us; speedup vs baseline: 1.9830x; 1.0122x over previous
//
#include <hip/hip_runtime.h>
#include <math.h>

typedef short short8 __attribute__((ext_vector_type(8)));
typedef float f32x4 __attribute__((ext_vector_type(4)));

// ---------------- helpers ----------------
__device__ __forceinline__ float block_reduce(float v, float* red) {
  int tid = threadIdx.x;
  red[tid] = v; __syncthreads();
  for (int s = 128; s >= 1; s >>= 1) {
    if (tid < s) red[tid] += red[tid + s];
    __syncthreads();
  }
  float r = red[0];
  __syncthreads();
  return r;
}

// f32 -> (hi bf16, lo bf16). hi = round-half-up; lo = exact residual truncated.
__device__ __forceinline__ void cvt1(float x, unsigned short& h, unsigned short& l) {
  unsigned u = __float_as_uint(x);
  unsigned hb = (u + 0x8000u) & 0xffff0000u;
  h = (unsigned short)(hb >> 16);
  l = (unsigned short)(__float_as_uint(x - __uint_as_float(hb)) >> 16);
}

// pairwise-packed variant (elem a in low 16, b in high 16)
__device__ __forceinline__ void cvt2(float a, float b, unsigned& hp, unsigned& lp) {
  unsigned ua = __float_as_uint(a), ub = __float_as_uint(b);
  unsigned ha = (ua + 0x8000u) & 0xffff0000u;
  unsigned hb = (ub + 0x8000u) & 0xffff0000u;
  float la = a - __uint_as_float(ha);
  float lb = b - __uint_as_float(hb);
  hp = (ha >> 16) | hb;
  lp = (__float_as_uint(la) >> 16) | (__float_as_uint(lb) & 0xffff0000u);
}

// async global -> LDS, 16B per lane. LDS dest: wave-uniform base + lane*16.
// Global src: per-lane (carries the swizzle). Drained by __syncthreads (vmcnt0).
__device__ __forceinline__ void gl2l(const unsigned short* g, unsigned short* l) {
  __builtin_amdgcn_global_load_lds(
      (const __attribute__((address_space(1))) void*)g,
      (__attribute__((address_space(3))) void*)l, 16, 0, 0);
}

union U8 { unsigned u[4]; short8 s; };

__global__ __launch_bounds__(256) void sentinel_kernel(float* __restrict__ out, int n, float v) {
  int i = blockIdx.x * 256 + threadIdx.x;
  if (i < n) out[i] = v;
}

// ---------------- BatchNorm stats ----------------
__global__ __launch_bounds__(256) void bn_stats_kernel(
    const float* __restrict__ tok, const float* __restrict__ g,
    const float* __restrict__ bb, float* __restrict__ ss) {
  __shared__ float red[256];
  const int d = blockIdx.x;
  float sum = 0.f, sumsq = 0.f;
  for (int s = threadIdx.x; s < 4096; s += 256) {
    float v = tok[s * 64 + d];
    sum += v; sumsq += v * v;
  }
  sum = block_reduce(sum, red);
  sumsq = block_reduce(sumsq, red);
  if (threadIdx.x == 0) {
    float mu = sum * (1.f / 4096.f);
    float var = sumsq * (1.f / 4096.f) - mu * mu;
    float sc = g[d] * rsqrtf(fmaxf(var, 0.f) + 1e-5f);
    ss[d] = sc;
    ss[64 + d] = bb[d] - mu * sc;
  }
}

__global__ __launch_bounds__(256) void tn_kernel(
    const float* __restrict__ tok, const float* __restrict__ ss,
    float* __restrict__ tn) {
  int idx = blockIdx.x * 256 + threadIdx.x;
  int d = idx & 63;
  tn[idx] = tok[idx] * ss[d] + ss[64 + d];
}

__global__ __launch_bounds__(256) void reverse_kernel(
    const float* __restrict__ x0, float* __restrict__ x0r) {
  int idx = blockIdx.x * 256 + threadIdx.x;
  int row = idx >> 9, e = idx & 511;
  int b = row >> 10, t = row & 1023;
  x0r[idx] = x0[((size_t)((b << 10) + (1023 - t))) * 512 + e];
}

// ---------------- row LayerNorm, f32 out (N = 512 or 256) ----------------
__global__ __launch_bounds__(256) void ln_kernel(
    const float* __restrict__ x, const float* __restrict__ g,
    const float* __restrict__ b, float* __restrict__ out, int N) {
  __shared__ float red[256];
  const size_t r = blockIdx.x;
  const int tid = threadIdx.x;
  float v0 = x[r * N + tid];
  float v1 = (N > 256) ? x[r * N + 256 + tid] : 0.f;
  float sum = block_reduce(v0 + v1, red);
  float sumsq = block_reduce(v0 * v0 + v1 * v1, red);
  float mean = sum / (float)N;
  float var = sumsq / (float)N - mean * mean;
  float rs = rsqrtf(fmaxf(var, 0.f) + 1e-5f);
  out[r * N + tid] = (v0 - mean) * rs * g[tid] + b[tid];
  if (N > 256)
    out[r * N + 256 + tid] = (v1 - mean) * rs * g[256 + tid] + b[256 + tid];
}

// ---------------- row LayerNorm, N=512, bf16 hi/lo plane out ----------------
__global__ __launch_bounds__(256) void ln_pl(
    const float* __restrict__ x, const float* __restrict__ g,
    const float* __restrict__ b, unsigned short* __restrict__ oh,
    unsigned short* __restrict__ ol) {
  __shared__ float red[256];
  const size_t r = blockIdx.x;
  const int tid = threadIdx.x;
  float v0 = x[r * 512 + tid];
  float v1 = x[r * 512 + 256 + tid];
  float sum = block_reduce(v0 + v1, red);
  float sumsq = block_reduce(v0 * v0 + v1 * v1, red);
  float mean = sum * (1.f / 512.f);
  float var = sumsq * (1.f / 512.f) - mean * mean;
  float rs = rsqrtf(fmaxf(var, 0.f) + 1e-5f);
  float o0 = (v0 - mean) * rs * g[tid] + b[tid];
  float o1 = (v1 - mean) * rs * g[256 + tid] + b[256 + tid];
  unsigned short h0, l0, h1, l1;
  cvt1(o0, h0, l0); cvt1(o1, h1, l1);
  oh[r * 512 + tid] = h0;       ol[r * 512 + tid] = l0;
  oh[r * 512 + 256 + tid] = h1; ol[r * 512 + 256 + tid] = l1;
}

// ---------------- weight conversion: f32 [K][N] -> transposed planes [N][K] ----------------
__global__ __launch_bounds__(256) void convw(
    const float* __restrict__ W, unsigned short* __restrict__ hi,
    unsigned short* __restrict__ lo, int K, int N, long dls) {
  int id = blockIdx.x * 256 + threadIdx.x;
  int total = (K >> 3) * N;
  if (id >= total) return;
  int c = id / N, n = id - c * N;
  const float* Wp = W + (size_t)blockIdx.y * K * N;
  size_t doff = (size_t)blockIdx.y * dls + (size_t)n * K + c * 8;
  unsigned short h8[8], l8[8];
#pragma unroll
  for (int j = 0; j < 8; ++j) {
    float xv = Wp[(size_t)(c * 8 + j) * N + n];
    cvt1(xv, h8[j], l8[j]);
  }
  uint4 hv = make_uint4(h8[0] | ((unsigned)h8[1] << 16), h8[2] | ((unsigned)h8[3] << 16),
                        h8[4] | ((unsigned)h8[5] << 16), h8[6] | ((unsigned)h8[7] << 16));
  uint4 lv = make_uint4(l8[0] | ((unsigned)l8[1] << 16), l8[2] | ((unsigned)l8[3] << 16),
                        l8[4] | ((unsigned)l8[5] << 16), l8[6] | ((unsigned)l8[7] << 16));
  *reinterpret_cast<uint4*>(hi + doff) = hv;
  *reinterpret_cast<uint4*>(lo + doff) = lv;
}

// --------- small GEMM (f32): out[M,N] = A@W + bias (act) ---------
#define BK 16
template <int ACT>  // 0 none, 1 gelu(exact), 2 tanh
__global__ __launch_bounds__(256) void gemm3(
    const float* __restrict__ A, const float* __restrict__ W,
    const float* __restrict__ bias, const float* resid,
    float* out, int M, int N, int K) {
  __shared__ float As[BK][64 + 4];
  __shared__ float Bs[BK][64 + 4];
  const int tid = threadIdx.x;
  const int tx = tid & 15, ty = tid >> 4;
  const int n0 = blockIdx.x * 64, m0 = blockIdx.y * 64;
  float acc[4][4] = {};
  for (int k0 = 0; k0 < K; k0 += BK) {
    {
      int m = tid >> 2, kq = tid & 3;
      float4 a4 = *reinterpret_cast<const float4*>(A + (size_t)(m0 + m) * K + k0 + kq * 4);
      As[kq * 4 + 0][m] = a4.x; As[kq * 4 + 1][m] = a4.y;
      As[kq * 4 + 2][m] = a4.z; As[kq * 4 + 3][m] = a4.w;
    }
    {
      int kk = tid >> 4, nq = tid & 15;
      float4 b4 = *reinterpret_cast<const float4*>(W + (size_t)(k0 + kk) * N + n0 + nq * 4);
      Bs[kk][nq * 4 + 0] = b4.x; Bs[kk][nq * 4 + 1] = b4.y;
      Bs[kk][nq * 4 + 2] = b4.z; Bs[kk][nq * 4 + 3] = b4.w;
    }
    __syncthreads();
#pragma unroll
    for (int kq = 0; kq < BK; ++kq) {
      float4 av = *reinterpret_cast<const float4*>(&As[kq][ty * 4]);
      float4 bv = *reinterpret_cast<const float4*>(&Bs[kq][tx * 4]);
      acc[0][0] += av.x * bv.x; acc[0][1] += av.x * bv.y; acc[0][2] += av.x * bv.z; acc[0][3] += av.x * bv.w;
      acc[1][0] += av.y * bv.x; acc[1][1] += av.y * bv.y; acc[1][2] += av.y * bv.z; acc[1][3] += av.y * bv.w;
      acc[2][0] += av.z * bv.x; acc[2][1] += av.z * bv.y; acc[2][2] += av.z * bv.z; acc[2][3] += av.z * bv.w;
      acc[3][0] += av.w * bv.x; acc[3][1] += av.w * bv.y; acc[3][2] += av.w * bv.z; acc[3][3] += av.w * bv.w;
    }
    __syncthreads();
  }
#pragma unroll
  for (int i = 0; i < 4; ++i) {
    int m = m0 + ty * 4 + i;
#pragma unroll
    for (int j = 0; j < 4; ++j) {
      int n = n0 + tx * 4 + j;
      float v = acc[i][j] + bias[n];
      if (resid) v += resid[(size_t)m * N + n];
      if (ACT == 1) v = 0.5f * v * (1.f + erff(v * 0.70710678118654752f));
      if (ACT == 2) v = tanhf(v);
      out[(size_t)m * N + n] = v;
    }
  }
}

// --------- MFMA GEMM over pre-split bf16 planes. 128x128x32 tiles, 4 waves. ---------
// Staging via global_load_lds (16B/lane) into double-buffered LDS; one barrier per
// K-step. Wave w owns plane w (0=Ah 1=Al 2=Bh 3=Bl). XOR slot swizzle carried on
// the per-lane global address; LDS linear; frag ds_read_b128 conflict-free.
// ACT: 0 none, 1 gelu, 2 tanh. OUTMODE: 0 f32, 1 planes, 2 both.
// ATOMIC: f32 atomicAdd into Cf (bias added by z==0). BIAS3: b0/b1/b2 512-wide sections.
// QKV: attention epilogue — Q cols (n0<512): planes scaled 1/8; K cols: planes;
//      V cols (n0>=1024): transposed vT planes [b][h][d][token] (uint2-packed).
template <int ACT, int OUTMODE, int ATOMIC, int BIAS3, int QKV>
__global__ __launch_bounds__(256, 2) void gemm_bf(
    const unsigned short* __restrict__ Ahp, const unsigned short* __restrict__ Alp,
    const unsigned short* __restrict__ Bhp, const unsigned short* __restrict__ Blp,
    const float* __restrict__ b0, const float* __restrict__ b1, const float* __restrict__ b2,
    float* __restrict__ Cf, unsigned short* __restrict__ Chp, unsigned short* __restrict__ Clp,
    unsigned short* __restrict__ vth, unsigned short* __restrict__ vtl,
    int M, int N, int K, int KZ) {
  // [buf][plane][row][32 ushorts]: 2 x 32KB
  __shared__ __align__(16) unsigned short LDS[2][4][128][32];
  const int tid = threadIdx.x;
  const int lane = tid & 63, wid = tid >> 6;
  const int wr = wid >> 1, wc = wid & 1;
  const int lr = lane & 15, lq = lane >> 4;

  // XCD swizzle over (x,y)
  const int gx = gridDim.x;
  int lin = blockIdx.y * gx + blockIdx.x;
  int qch = (gx * gridDim.y) >> 3;
  int swz = (lin & 7) * qch + (lin >> 3);
  const int nb = swz % gx, mb = swz / gx;
  const int n0 = nb * 128, m0 = mb * 128;
  const int kbase = blockIdx.z * KZ, kend = kbase + KZ;

  f32x4 acc[4][4];
#pragma unroll
  for (int i = 0; i < 4; ++i)
#pragma unroll
    for (int j = 0; j < 4; ++j) { acc[i][j][0] = 0.f; acc[i][j][1] = 0.f; acc[i][j][2] = 0.f; acc[i][j][3] = 0.f; }

  // wave wid stages plane wid
  const unsigned short* gplane =
      (wid == 0) ? Ahp + (size_t)m0 * K :
      (wid == 1) ? Alp + (size_t)m0 * K :
      (wid == 2) ? Bhp + (size_t)n0 * K : Blp + (size_t)n0 * K;
  const int srow = lane >> 2;   // 0..15 within a 16-row chunk
  const int sphys = lane & 3;   // physical 16B slot

  auto stage = [&](int buf, int k0) {
#pragma unroll
    for (int j = 0; j < 8; ++j) {
      int row = j * 16 + srow;
      int logslot = sphys ^ ((row >> 1) & 3);
      gl2l(gplane + (size_t)row * K + k0 + logslot * 8, &LDS[buf][wid][j * 16][0]);
    }
  };

  stage(0, kbase);
  __syncthreads();
  int cur = 0;
  for (int k0 = kbase; k0 < kend; k0 += 32) {
    if (k0 + 32 < kend) stage(cur ^ 1, k0 + 32);
    short8 ah[4], al[4], bh[4], bl[4];
#pragma unroll
    for (int mi = 0; mi < 4; ++mi) {
      int row = wr * 64 + mi * 16 + lr;
      int off = (lq ^ ((row >> 1) & 3)) * 8;
      ah[mi] = *reinterpret_cast<const short8*>(&LDS[cur][0][row][off]);
      al[mi] = *reinterpret_cast<const short8*>(&LDS[cur][1][row][off]);
    }
#pragma unroll
    for (int ni = 0; ni < 4; ++ni) {
      int n = wc * 64 + ni * 16 + lr;
      int off = (lq ^ ((n >> 1) & 3)) * 8;
      bh[ni] = *reinterpret_cast<const short8*>(&LDS[cur][2][n][off]);
      bl[ni] = *reinterpret_cast<const short8*>(&LDS[cur][3][n][off]);
    }
#pragma unroll
    for (int mi = 0; mi < 4; ++mi)
#pragma unroll
      for (int ni = 0; ni < 4; ++ni) {
        acc[mi][ni] = __builtin_amdgcn_mfma_f32_16x16x32_bf16(ah[mi], bh[ni], acc[mi][ni], 0, 0, 0);
        acc[mi][ni] = __builtin_amdgcn_mfma_f32_16x16x32_bf16(ah[mi], bl[ni], acc[mi][ni], 0, 0, 0);
        acc[mi][ni] = __builtin_amdgcn_mfma_f32_16x16x32_bf16(al[mi], bh[ni], acc[mi][ni], 0, 0, 0);
      }
    __syncthreads();   // drains prefetch (vmcnt0) + frees cur for next stage
    cur ^= 1;
  }

  // ---- epilogue ----
  if (QKV) {
    const float* bsec = (n0 < 512) ? b0 : (n0 < 1024 ? b1 : b2);
    const int bof = (n0 & 511) - n0;
    if (n0 < 1024) {     // Q (scaled 1/8) and K sections -> planes [token][1536]
      const float scale = (n0 < 512) ? 0.125f : 1.f;
#pragma unroll
      for (int mi = 0; mi < 4; ++mi)
#pragma unroll
        for (int r = 0; r < 4; ++r) {
          int grow = m0 + wr * 64 + mi * 16 + lq * 4 + r;
#pragma unroll
          for (int ni = 0; ni < 4; ++ni) {
            int col = n0 + wc * 64 + ni * 16 + lr;
            float v = (acc[mi][ni][r] + bsec[col + bof]) * scale;
            unsigned short hv, lv;
            cvt1(v, hv, lv);
            Chp[(size_t)grow * N + col] = hv;
            Clp[(size_t)grow * N + col] = lv;
          }
        }
    } else {             // V section -> transposed vT planes [b][h][d][token]
#pragma unroll
      for (int mi = 0; mi < 4; ++mi) {
        int t0 = m0 + wr * 64 + mi * 16 + lq * 4;
        int bb = t0 >> 10, tt = t0 & 1023;
#pragma unroll
        for (int ni = 0; ni < 4; ++ni) {
          int col = n0 + wc * 64 + ni * 16 + lr;
          float bias = bsec[col + bof];
          int hh_ = (col - 1024) >> 6, dd = (col - 1024) & 63;
          unsigned short h4[4], l4[4];
#pragma unroll
          for (int r = 0; r < 4; ++r) cvt1(acc[mi][ni][r] + bias, h4[r], l4[r]);
          size_t off = ((size_t)((bb * 8 + hh_) * 64 + dd)) * 1024 + tt;
          *reinterpret_cast<uint2*>(vth + off) = make_uint2(
              h4[0] | ((unsigned)h4[1] << 16), h4[2] | ((unsigned)h4[3] << 16));
          *reinterpret_cast<uint2*>(vtl + off) = make_uint2(
              l4[0] | ((unsigned)l4[1] << 16), l4[2] | ((unsigned)l4[3] << 16));
        }
      }
    }
    return;
  }
  const float* bsec = b0;
  int bof = 0;
  if (BIAS3) { bsec = (n0 < 512) ? b0 : (n0 < 1024 ? b1 : b2); bof = (n0 & 511) - n0; }
#pragma unroll
  for (int mi = 0; mi < 4; ++mi) {
#pragma unroll
    for (int r = 0; r < 4; ++r) {
      int grow = m0 + wr * 64 + mi * 16 + lq * 4 + r;
#pragma unroll
      for (int ni = 0; ni < 4; ++ni) {
        int col = n0 + wc * 64 + ni * 16 + lr;
        float v = acc[mi][ni][r];
        float bias = BIAS3 ? bsec[col + bof] : b0[col];
        if (ATOMIC) {
          if (blockIdx.z == 0) v += bias;
          atomicAdd(&Cf[(size_t)grow * N + col], v);
        } else {
          v += bias;
          if (ACT == 1) v = 0.5f * v * (1.f + erff(v * 0.70710678118654752f));
          if (ACT == 2) v = tanhf(v);
          if (OUTMODE == 0 || OUTMODE == 2) Cf[(size_t)grow * N + col] = v;
          if (OUTMODE >= 1) {
            unsigned short hv, lv;
            cvt1(v, hv, lv);
            Chp[(size_t)grow * N + col] = hv;
            Clp[(size_t)grow * N + col] = lv;
          }
        }
      }
    }
  }
}

// ---------------- attention: MFMA flash over pre-split planes ----------------
// Q/K read from qkv planes [4096][1536] (Q pre-scaled 1/8), V from transposed
// vT planes [b][h][d][1024]. ALL staging via global_load_lds with the XOR slot
// swizzle on the per-lane global address — zero conversion VALU in the loop.
// Writes yb as bf16 hi/lo planes.
__global__ __launch_bounds__(256, 3) void attn_mfma(
    const unsigned short* __restrict__ qkvh, const unsigned short* __restrict__ qkvl,
    const unsigned short* __restrict__ vth, const unsigned short* __restrict__ vtl,
    const float* __restrict__ mask,
    unsigned short* __restrict__ ybh, unsigned short* __restrict__ ybl, int rev) {
  __shared__ __align__(16) unsigned short QK[2][4096];  // Q staging, then K (hi,lo)
  __shared__ __align__(16) unsigned short VT[2][4096];  // V^T (hi,lo)
  __shared__ float PU[64 * 68];                         // P (f32)
  __shared__ float km[64];

  const int tid = threadIdx.x;
  const int lane = tid & 63, w = tid >> 6;
  const int lr = lane & 15, lq = lane >> 4;

  const int id = blockIdx.x;          // complementary-pair mapping
  const int top = id >> 8;
  const int r5 = id & 255;
  const int qt = top ? (15 - (r5 >> 4)) : (r5 >> 4);
  const int bh_ = (r5 & 15) | (top << 4);
  const int b = bh_ >> 3, h = bh_ & 7;

  // ---- stage Q planes via global_load_lds (pre-scaled in QKV gemm) ----
  {
    const unsigned short* src = (w < 2) ? qkvh : qkvl;
    unsigned short* dst = QK[w >> 1];
    int half = w & 1;
#pragma unroll
    for (int j = 0; j < 4; ++j) {
      int chunk = half * 256 + j * 64 + lane;
      int row = chunk >> 3, p = chunk & 7;
      int slot = p ^ (row & 7);
      gl2l(src + (size_t)(b * 1024 + qt * 64 + row) * 1536 + h * 64 + slot * 8,
           dst + (half * 256 + j * 64) * 8);
    }
  }
  __syncthreads();
  short8 qa_h[2], qa_l[2];
#pragma unroll
  for (int ks = 0; ks < 2; ++ks) {
    int row = w * 16 + lr;
    int phys = (lq + ks * 4) ^ (row & 7);
    qa_h[ks] = *reinterpret_cast<const short8*>(&QK[0][row * 64 + phys * 8]);
    qa_l[ks] = *reinterpret_cast<const short8*>(&QK[1][row * 64 + phys * 8]);
  }
  __syncthreads();  // QK region now free for K tiles

  float m_[4], l_[4] = {0.f, 0.f, 0.f, 0.f};
  f32x4 o_[4];
#pragma unroll
  for (int r = 0; r < 4; ++r) m_[r] = -1e30f;
#pragma unroll
  for (int df = 0; df < 4; ++df) { o_[df][0] = 0.f; o_[df][1] = 0.f; o_[df][2] = 0.f; o_[df][3] = 0.f; }

  for (int kt = 0; kt <= qt; ++kt) {
    // ---- stage K + V^T via global_load_lds: wave w owns region w ----
    if (w < 2) {
      const unsigned short* src = (w == 0) ? qkvh : qkvl;
      unsigned short* dst = QK[w];
#pragma unroll
      for (int j = 0; j < 8; ++j) {
        int chunk = j * 64 + lane;
        int row = chunk >> 3, p = chunk & 7;
        int slot = p ^ (row & 7);
        gl2l(src + (size_t)(b * 1024 + kt * 64 + row) * 1536 + 512 + h * 64 + slot * 8,
             dst + j * 512);
      }
    } else {
      const unsigned short* src = (w == 2) ? vth : vtl;
      unsigned short* dst = VT[w - 2];
#pragma unroll
      for (int j = 0; j < 8; ++j) {
        int chunk = j * 64 + lane;
        int row = chunk >> 3, p = chunk & 7;   // row = d 0..63
        int slot = p ^ (row & 7);
        gl2l(src + (size_t)((b * 8 + h) * 64 + row) * 1024 + kt * 64 + slot * 8,
             dst + j * 512);
      }
    }
    if (tid < 64) {
      int s = kt * 64 + tid;
      km[tid] = mask[b * 1024 + (rev ? (1023 - s) : s)];
    }
    __syncthreads();

    // ---- S = Q K^T (x3 MFMA) ----
    f32x4 sacc[4];
#pragma unroll
    for (int kf = 0; kf < 4; ++kf) { sacc[kf][0] = 0.f; sacc[kf][1] = 0.f; sacc[kf][2] = 0.f; sacc[kf][3] = 0.f; }
#pragma unroll
    for (int ks = 0; ks < 2; ++ks) {
#pragma unroll
      for (int kf = 0; kf < 4; ++kf) {
        int col = kf * 16 + lr;
        int phys = (lq + ks * 4) ^ (lr & 7);
        short8 kbh = *reinterpret_cast<const short8*>(&QK[0][col * 64 + phys * 8]);
        short8 kbl = *reinterpret_cast<const short8*>(&QK[1][col * 64 + phys * 8]);
        sacc[kf] = __builtin_amdgcn_mfma_f32_16x16x32_bf16(qa_h[ks], kbh, sacc[kf], 0, 0, 0);
        sacc[kf] = __builtin_amdgcn_mfma_f32_16x16x32_bf16(qa_h[ks], kbl, sacc[kf], 0, 0, 0);
        sacc[kf] = __builtin_amdgcn_mfma_f32_16x16x32_bf16(qa_l[ks], kbh, sacc[kf], 0, 0, 0);
      }
    }

    // ---- online softmax in registers ----
    const bool diag = (kt == qt);
    float kmv[4];
#pragma unroll
    for (int kf = 0; kf < 4; ++kf) kmv[kf] = km[kf * 16 + lr];
#pragma unroll
    for (int r = 0; r < 4; ++r) {
      int fi = (w * 16 + lq * 4 + r) >> 3;
      float mt = -1e30f;
#pragma unroll
      for (int kf = 0; kf < 4; ++kf) {
        int key = kf * 16 + lr;
        bool ok = (kmv[kf] > 0.f) && (!diag || ((key >> 3) <= fi));
        float x = ok ? sacc[kf][r] : -1e30f;
        sacc[kf][r] = x;
        mt = fmaxf(mt, x);
      }
      mt = fmaxf(mt, __shfl_xor(mt, 1, 16));
      mt = fmaxf(mt, __shfl_xor(mt, 2, 16));
      mt = fmaxf(mt, __shfl_xor(mt, 4, 16));
      mt = fmaxf(mt, __shfl_xor(mt, 8, 16));
      float mn = fmaxf(m_[r], mt);
      float al = __expf(m_[r] - mn);
      m_[r] = mn;
      float rs = 0.f;
#pragma unroll
      for (int kf = 0; kf < 4; ++kf) {
        float sv = sacc[kf][r];
        float p = (sv > -1e29f) ? __expf(sv - mn) : 0.f;
        sacc[kf][r] = p;
        rs += p;
      }
      rs += __shfl_xor(rs, 1, 16);
      rs += __shfl_xor(rs, 2, 16);
      rs += __shfl_xor(rs, 4, 16);
      rs += __shfl_xor(rs, 8, 16);
      l_[r] = l_[r] * al + rs;
#pragma unroll
      for (int df = 0; df < 4; ++df) o_[df][r] *= al;
    }
    // ---- write P (f32, 68-stride) ----
#pragma unroll
    for (int kf = 0; kf < 4; ++kf)
#pragma unroll
      for (int r = 0; r < 4; ++r)
        PU[(w * 16 + lq * 4 + r) * 68 + kf * 16 + lr] = sacc[kf][r];
    __syncthreads();

    // ---- O += P V (x3 MFMA) ----
#pragma unroll
    for (int ks = 0; ks < 2; ++ks) {
      const float* pp = &PU[(w * 16 + lr) * 68 + ks * 32 + lq * 8];
      float4 p0 = *reinterpret_cast<const float4*>(pp);
      float4 p1 = *reinterpret_cast<const float4*>(pp + 4);
      U8 th, tl;
      cvt2(p0.x, p0.y, th.u[0], tl.u[0]);
      cvt2(p0.z, p0.w, th.u[1], tl.u[1]);
      cvt2(p1.x, p1.y, th.u[2], tl.u[2]);
      cvt2(p1.z, p1.w, th.u[3], tl.u[3]);
      short8 pa_h = th.s, pa_l = tl.s;
#pragma unroll
      for (int df = 0; df < 4; ++df) {
        int col = df * 16 + lr;
        int phys = (lq + ks * 4) ^ (lr & 7);
        short8 vbh = *reinterpret_cast<const short8*>(&VT[0][col * 64 + phys * 8]);
        short8 vbl = *reinterpret_cast<const short8*>(&VT[1][col * 64 + phys * 8]);
        o_[df] = __builtin_amdgcn_mfma_f32_16x16x32_bf16(pa_h, vbh, o_[df], 0, 0, 0);
        o_[df] = __builtin_amdgcn_mfma_f32_16x16x32_bf16(pa_h, vbl, o_[df], 0, 0, 0);
        o_[df] = __builtin_amdgcn_mfma_f32_16x16x32_bf16(pa_l, vbh, o_[df], 0, 0, 0);
      }
    }
    __syncthreads();
  }

  // ---- normalize + write planes ----
#pragma unroll
  for (int r = 0; r < 4; ++r) {
    float inv = 1.f / fmaxf(l_[r], 1e-30f);
    int qrow = qt * 64 + w * 16 + lq * 4 + r;
#pragma unroll
    for (int df = 0; df < 4; ++df) {
      float val = o_[df][r] * inv;
      unsigned short hv, lv;
      cvt1(val, hv, lv);
      size_t idx = (size_t)(b * 1024 + qrow) * 512 + h * 64 + df * 16 + lr;
      ybh[idx] = hv; ybl[idx] = lv;
    }
  }
}

// ---------------- frame mean (+ FLOAT32 output write) ----------------
__global__ __launch_bounds__(256) void frame_mean_kernel(
    const float* __restrict__ xo, float* __restrict__ xf,
    float* __restrict__ outf) {
  int row = blockIdx.x;       // b*128+tf
  int o = threadIdx.x;
  float s = 0.f;
#pragma unroll
  for (int c = 0; c < 8; ++c) s += xo[((size_t)row * 8 + c) * 256 + o];
  s *= 0.125f;
  xf[row * 256 + o] = s;
  if (outf) outf[row * 256 + o] = s;
}

// ---------------- losses ----------------
__global__ __launch_bounds__(256) void loss_reg_kernel(
    const float* __restrict__ pd, const float* __restrict__ tok,
    const float* __restrict__ mask, float* __restrict__ acc, int rev) {
  __shared__ float red[256];
  float local = 0.f;
  for (int idx = blockIdx.x * 256 + threadIdx.x; idx < 260096; idx += gridDim.x * 256) {
    int b = idx / 65024, r2 = idx % 65024;
    int t = r2 >> 6, d = r2 & 63;
    float pred = pd[((size_t)((b << 10) + t)) * 64 + d] * mask[(b << 10) + t];
    int tt = rev ? (1015 - t) : (t + 8);
    float tgt = tok[((size_t)((b << 10) + tt)) * 64 + d] * mask[(b << 10) + tt];
    float df = pred - tgt;
    local += df * df;
  }
  float s = block_reduce(local, red);
  if (threadIdx.x == 0) atomicAdd(acc, s);
}

__global__ __launch_bounds__(256) void loss_fr_kernel(
    const float* __restrict__ pf, const float* __restrict__ tok,
    const float* __restrict__ mask, float* __restrict__ acc, int rev) {
  __shared__ float red[256];
  float local = 0.f;
  for (int idx = blockIdx.x * 256 + threadIdx.x; idx < 260096; idx += gridDim.x * 256) {
    int b = idx / 65024, r2 = idx % 65024;
    int i = r2 >> 9, u = r2 & 511;
    float pred = pf[((size_t)(b * 128 + i)) * 512 + u];
    int c = u >> 6;
    int t = rev ? ((126 - i) * 8 + c) : ((i + 1) * 8 + c);
    float tgt = tok[((size_t)((b << 10) + t)) * 64 + (u & 63)] * mask[(b << 10) + t];
    float df = pred - tgt;
    local += df * df;
  }
  float s = block_reduce(local, red);
  if (threadIdx.x == 0) atomicAdd(acc, s);
}

__global__ void finalize_kernel(const float* __restrict__ acc, float* __restrict__ out) {
  int i = threadIdx.x;
  if (i < 4) out[131072 + i] = acc[i] * (1.0f / 260096.0f);
}

extern "C" void kernel_launch(void* const* d_in, const int* in_sizes, int n_in,
                              void* d_out, int out_size, void* d_ws, size_t ws_size,
                              hipStream_t stream) {
  float* ws = (float*)d_ws;
  const size_t OFF_SS   = 0;
  const size_t OFF_LACC = 128;
  const size_t OFF_TN   = 256;
  const size_t OFF_X0   = 262400;
  const size_t OFF_X0R  = 2359552;
  const size_t OFF_X    = 4456704;
  const size_t OFF_HPL  = 6553856;    // h planes (hi/lo)
  const size_t OFF_QKV  = 8651008;    // qkv planes (hi 3145728 fl, lo 3145728 fl); u planes alias
  const size_t OFF_YB   = 14942464;   // yb planes 2097152 fl
  const size_t OFF_XO   = 17039616;   // f32 1048576
  const size_t OFF_XOPL = 18088192;   // xo planes 1048576 fl
  const size_t OFF_HD   = 19136768;
  const size_t OFF_HD2  = 20185344;
  const size_t OFF_PD   = 21233920;
  const size_t OFF_XF   = 21496064;
  const size_t OFF_HF   = 21627136;
  const size_t OFF_HF2  = 21758208;
  const size_t OFF_PF   = 21889280;
  const size_t OFF_VT   = 22151424;   // vT planes 2097152 fl
  const size_t OFF_WB   = 24248576;
  const size_t TOTAL_MIN = OFF_WB + 1048576;    // JIT scratch mode (~101 MB)
  const size_t TOTAL_BIG = OFF_WB + 19070976;   // full weight-plane mode (~173 MB)

  float* ss   = ws + OFF_SS;
  float* lacc = ws + OFF_LACC;
  float* tn   = ws + OFF_TN;
  float* x0   = ws + OFF_X0;
  float* x0r  = ws + OFF_X0R;
  float* x    = ws + OFF_X;
  unsigned short* hh = (unsigned short*)(ws + OFF_HPL);
  unsigned short* hl = hh + 2097152;
  unsigned short* qkvh = (unsigned short*)(ws + OFF_QKV);
  unsigned short* qkvl = qkvh + 6291456;
  unsigned short* uh = (unsigned short*)(ws + OFF_QKV);   // alias (MLP phase only)
  unsigned short* ul = uh + 8388608;
  unsigned short* ybh = (unsigned short*)(ws + OFF_YB);
  unsigned short* ybl = ybh + 2097152;
  float* xo   = ws + OFF_XO;
  unsigned short* xoh = (unsigned short*)(ws + OFF_XOPL);
  unsigned short* xol = xoh + 1048576;
  float* hd   = ws + OFF_HD;
  float* hd2  = ws + OFF_HD2;
  float* pd   = ws + OFF_PD;
  float* xf   = ws + OFF_XF;
  float* hf   = ws + OFF_HF;
  float* hf2  = ws + OFF_HF2;
  float* pf   = ws + OFF_PF;
  unsigned short* vth = (unsigned short*)(ws + OFF_VT);
  unsigned short* vtl = vth + 2097152;
  unsigned short* wb16 = (unsigned short*)(ws + OFF_WB);
  float* out_f = (float*)d_out;   // OUTPUT IS FLOAT32

  static const int EXPECTED[39] = {
      262144, 4096, 4096, 64, 64, 32768, 512, 3072, 3072, 3072, 3072,
      1572864, 3072, 1572864, 3072, 1572864, 3072, 1572864, 3072,
      6291456, 12288, 6291456, 3072, 512, 512, 131072, 256, 65536, 256,
      256, 256, 16384, 64, 65536, 256, 256, 256, 131072, 512};
  bool manifest_ok = (n_in == 39) && (ws_size >= TOTAL_MIN * sizeof(float));
  if (manifest_ok)
    for (int i = 0; i < 39; ++i)
      if (in_sizes[i] != EXPECTED[i]) { manifest_ok = false; break; }
  if (!manifest_ok) {
    hipLaunchKernelGGL(sentinel_kernel, dim3((out_size + 255) / 256), dim3(256), 0, stream,
                       out_f, out_size, 2000.0f);
    return;
  }
  const bool bigws = ws_size >= TOTAL_BIG * sizeof(float);

  const float* tok    = (const float*)d_in[0];
  const float* mask   = (const float*)d_in[2];
  const float* bn_g   = (const float*)d_in[3];
  const float* bn_b   = (const float*)d_in[4];
  const float* We     = (const float*)d_in[5];
  const float* be     = (const float*)d_in[6];
  const float* ln1_g  = (const float*)d_in[7];
  const float* ln1_b  = (const float*)d_in[8];
  const float* ln2_g  = (const float*)d_in[9];
  const float* ln2_b  = (const float*)d_in[10];
  const float* Wq     = (const float*)d_in[11];
  const float* bq     = (const float*)d_in[12];
  const float* Wk     = (const float*)d_in[13];
  const float* bk     = (const float*)d_in[14];
  const float* Wv     = (const float*)d_in[15];
  const float* bv     = (const float*)d_in[16];
  const float* Wo     = (const float*)d_in[17];
  const float* bo     = (const float*)d_in[18];
  const float* W1     = (const float*)d_in[19];
  const float* b1     = (const float*)d_in[20];
  const float* W2     = (const float*)d_in[21];
  const float* b2     = (const float*)d_in[22];
  const float* lnf_g  = (const float*)d_in[23];
  const float* lnf_b  = (const float*)d_in[24];
  const float* Wp     = (const float*)d_in[25];
  const float* bp     = (const float*)d_in[26];
  const float* Wd1    = (const float*)d_in[27];
  const float* bd1    = (const float*)d_in[28];
  const float* lnd_g  = (const float*)d_in[29];
  const float* lnd_b  = (const float*)d_in[30];
  const float* Wd2    = (const float*)d_in[31];
  const float* bd2    = (const float*)d_in[32];
  const float* Wf1    = (const float*)d_in[33];
  const float* bf1    = (const float*)d_in[34];
  const float* lnfr_g = (const float*)d_in[35];
  const float* lnfr_b = (const float*)d_in[36];
  const float* Wf2    = (const float*)d_in[37];
  const float* bf2    = (const float*)d_in[38];

  // weight-plane pointers (big mode), ushort offsets
  unsigned short* wqkv_h = wb16;
  unsigned short* wqkv_l = wb16 + 4718592;
  unsigned short* wo_h   = wb16 + 9437184;
  unsigned short* wo_l   = wb16 + 11010048;
  unsigned short* w1_h   = wb16 + 12582912;
  unsigned short* w1_l   = wb16 + 18874368;
  unsigned short* w2_h   = wb16 + 25165824;
  unsigned short* w2_l   = wb16 + 31457280;
  unsigned short* wp_h   = wb16 + 37748736;
  unsigned short* wp_l   = wb16 + 37879808;
  unsigned short* wd1_h  = wb16 + 38010880;
  unsigned short* wd1_l  = wb16 + 38076416;
  unsigned short* scr    = wb16;   // JIT scratch (small mode)

  auto G = [&](int act, const float* A, const float* W, const float* bias,
               const float* resid, float* out, int M, int N, int K) {
    dim3 g(N / 64, M / 64), b(256);
    if (act == 0) hipLaunchKernelGGL((gemm3<0>), g, b, 0, stream, A, W, bias, resid, out, M, N, K);
    else if (act == 1) hipLaunchKernelGGL((gemm3<1>), g, b, 0, stream, A, W, bias, resid, out, M, N, K);
    else hipLaunchKernelGGL((gemm3<2>), g, b, 0, stream, A, W, bias, resid, out, M, N, K);
  };
  auto CONV = [&](const float* W, unsigned short* hi, unsigned short* lo,
                  int K, int N, int layers, long dls) {
    int blocks = ((K >> 3) * N + 255) / 256;
    hipLaunchKernelGGL(convw, dim3(blocks, layers), dim3(256), 0, stream, W, hi, lo, K, N, dls);
  };

  hipMemsetAsync(lacc, 0, 4 * sizeof(float), stream);
  if (bigws) {  // one-time full weight conversion
    CONV(Wq, wqkv_h,          wqkv_l,          512, 512, 6, 786432);
    CONV(Wk, wqkv_h + 262144, wqkv_l + 262144, 512, 512, 6, 786432);
    CONV(Wv, wqkv_h + 524288, wqkv_l + 524288, 512, 512, 6, 786432);
    CONV(Wo, wo_h, wo_l, 512, 512, 6, 262144);
    CONV(W1, w1_h, w1_l, 512, 2048, 6, 1048576);
    CONV(W2, w2_h, w2_l, 2048, 512, 6, 1048576);
    CONV(Wp, wp_h, wp_l, 512, 256, 1, 0);
    CONV(Wd1, wd1_h, wd1_l, 256, 256, 1, 0);
  }
  hipLaunchKernelGGL(bn_stats_kernel, dim3(64), dim3(256), 0, stream, tok, bn_g, bn_b, ss);
  hipLaunchKernelGGL(tn_kernel, dim3(1024), dim3(256), 0, stream, tok, ss, tn);
  G(0, tn, We, be, nullptr, x0, 4096, 512, 64);
  hipLaunchKernelGGL(reverse_kernel, dim3(8192), dim3(256), 0, stream, x0, x0r);

  for (int dir = 0; dir < 2; ++dir) {
    const float* xin = dir ? x0r : x0;
    for (int l = 0; l < 6; ++l) {
      const float* xl = (l == 0) ? xin : x;
      hipLaunchKernelGGL(ln_pl, dim3(4096), dim3(256), 0, stream,
                         xl, ln1_g + l * 512, ln1_b + l * 512, hh, hl);
      // fused QKV GEMM, N=1536; attention-ready outputs (Q planes scaled, K planes, vT)
      const unsigned short *pqh, *pql;
      if (bigws) { pqh = wqkv_h + (size_t)l * 786432; pql = wqkv_l + (size_t)l * 786432; }
      else {
        CONV(Wq + (size_t)l * 262144, scr,          scr + 786432,          512, 512, 1, 0);
        CONV(Wk + (size_t)l * 262144, scr + 262144, scr + 786432 + 262144, 512, 512, 1, 0);
        CONV(Wv + (size_t)l * 262144, scr + 524288, scr + 786432 + 524288, 512, 512, 1, 0);
        pqh = scr; pql = scr + 786432;
      }
      hipLaunchKernelGGL((gemm_bf<0, 1, 0, 1, 1>), dim3(12, 32, 1), dim3(256), 0, stream,
                         hh, hl, pqh, pql, bq + l * 512, bk + l * 512, bv + l * 512,
                         nullptr, qkvh, qkvl, vth, vtl, 4096, 1536, 512, 512);
      // seed x with the residual for layer 0
      if (l == 0)
        hipMemcpyAsync(x, xin, 2097152 * sizeof(float), hipMemcpyDeviceToDevice, stream);
      hipLaunchKernelGGL(attn_mfma, dim3(512), dim3(256), 0, stream,
                         qkvh, qkvl, vth, vtl, mask, ybh, ybl, dir);
      // O-proj: split-K=2, atomicAdd into x (x pre-holds residual)
      const unsigned short *poh, *pol;
      if (bigws) { poh = wo_h + (size_t)l * 262144; pol = wo_l + (size_t)l * 262144; }
      else {
        CONV(Wo + (size_t)l * 262144, scr, scr + 262144, 512, 512, 1, 0);
        poh = scr; pol = scr + 262144;
      }
      hipLaunchKernelGGL((gemm_bf<0, 0, 1, 0, 0>), dim3(4, 32, 2), dim3(256), 0, stream,
                         ybh, ybl, poh, pol, bo + l * 512, nullptr, nullptr,
                         x, nullptr, nullptr, nullptr, nullptr, 4096, 512, 512, 256);
      hipLaunchKernelGGL(ln_pl, dim3(4096), dim3(256), 0, stream,
                         x, ln2_g + l * 512, ln2_b + l * 512, hh, hl);
      // MLP up + gelu, planes out
      const unsigned short *p1h, *p1l;
      if (bigws) { p1h = w1_h + (size_t)l * 1048576; p1l = w1_l + (size_t)l * 1048576; }
      else {
        CONV(W1 + (size_t)l * 1048576, scr, scr + 1048576, 512, 2048, 1, 0);
        p1h = scr; p1l = scr + 1048576;
      }
      hipLaunchKernelGGL((gemm_bf<1, 1, 0, 0, 0>), dim3(16, 32, 1), dim3(256), 0, stream,
                         hh, hl, p1h, p1l, b1 + l * 2048, nullptr, nullptr,
                         nullptr, uh, ul, nullptr, nullptr, 4096, 2048, 512, 512);
      // MLP down: split-K=2, atomicAdd into x
      const unsigned short *p2h, *p2l;
      if (bigws) { p2h = w2_h + (size_t)l * 1048576; p2l = w2_l + (size_t)l * 1048576; }
      else {
        CONV(W2 + (size_t)l * 1048576, scr, scr + 1048576, 2048, 512, 1, 0);
        p2h = scr; p2l = scr + 1048576;
      }
      hipLaunchKernelGGL((gemm_bf<0, 0, 1, 0, 0>), dim3(4, 32, 2), dim3(256), 0, stream,
                         uh, ul, p2h, p2l, b2 + l * 512, nullptr, nullptr,
                         x, nullptr, nullptr, nullptr, nullptr, 4096, 512, 2048, 1024);
    }
    hipLaunchKernelGGL(ln_pl, dim3(4096), dim3(256), 0, stream, x, lnf_g, lnf_b, hh, hl);
    // head projection (f32 + planes out) and decoder first layer (tanh)
    const unsigned short *pph, *ppl, *pdh, *pdl;
    if (bigws) { pph = wp_h; ppl = wp_l; }
    else { CONV(Wp, scr, scr + 131072, 512, 256, 1, 0); pph = scr; ppl = scr + 131072; }
    hipLaunchKernelGGL((gemm_bf<0, 2, 0, 0, 0>), dim3(2, 32, 1), dim3(256), 0, stream,
                       hh, hl, pph, ppl, bp, nullptr, nullptr,
                       xo, xoh, xol, nullptr, nullptr, 4096, 256, 512, 512);
    if (bigws) { pdh = wd1_h; pdl = wd1_l; }
    else { CONV(Wd1, scr, scr + 65536, 256, 256, 1, 0); pdh = scr; pdl = scr + 65536; }
    hipLaunchKernelGGL((gemm_bf<2, 0, 0, 0, 0>), dim3(2, 32, 1), dim3(256), 0, stream,
                       xoh, xol, pdh, pdl, bd1, nullptr, nullptr,
                       hd, nullptr, nullptr, nullptr, nullptr, 4096, 256, 256, 256);
    hipLaunchKernelGGL(ln_kernel, dim3(4096), dim3(256), 0, stream, hd, lnd_g, lnd_b, hd2, 256);
    G(0, hd2, Wd2, bd2, nullptr, pd, 4096, 64, 256);
    hipLaunchKernelGGL(loss_reg_kernel, dim3(256), dim3(256), 0, stream,
                       pd, tok, mask, lacc + (dir ? 1 : 0), dir);
    hipLaunchKernelGGL(frame_mean_kernel, dim3(512), dim3(256), 0, stream,
                       xo, xf, dir == 0 ? out_f : (float*)nullptr);
    G(2, xf, Wf1, bf1, nullptr, hf, 512, 256, 256);
    hipLaunchKernelGGL(ln_kernel, dim3(512), dim3(256), 0, stream, hf, lnfr_g, lnfr_b, hf2, 256);
    G(0, hf2, Wf2, bf2, nullptr, pf, 512, 512, 256);
    hipLaunchKernelGGL(loss_fr_kernel, dim3(256), dim3(256), 0, stream,
                       pf, tok, mask, lacc + (dir ? 3 : 2), dir);
  }
  hipLaunchKernelGGL(finalize_kernel, dim3(1), dim3(64), 0, stream, lacc, out_f);
}

// Round 8
// 2566.017 us; speedup vs baseline: 2.1116x; 1.0649x over previous
//
#include <hip/hip_runtime.h>
#include <math.h>

typedef short short8 __attribute__((ext_vector_type(8)));
typedef float f32x4 __attribute__((ext_vector_type(4)));

// ---------------- helpers ----------------
__device__ __forceinline__ float block_reduce(float v, float* red) {
  int tid = threadIdx.x;
  red[tid] = v; __syncthreads();
  for (int s = 128; s >= 1; s >>= 1) {
    if (tid < s) red[tid] += red[tid + s];
    __syncthreads();
  }
  float r = red[0];
  __syncthreads();
  return r;
}

// f32 -> (hi bf16, lo bf16). hi = round-half-up; lo = exact residual truncated.
__device__ __forceinline__ void cvt1(float x, unsigned short& h, unsigned short& l) {
  unsigned u = __float_as_uint(x);
  unsigned hb = (u + 0x8000u) & 0xffff0000u;
  h = (unsigned short)(hb >> 16);
  l = (unsigned short)(__float_as_uint(x - __uint_as_float(hb)) >> 16);
}

// pairwise-packed variant (elem a in low 16, b in high 16)
__device__ __forceinline__ void cvt2(float a, float b, unsigned& hp, unsigned& lp) {
  unsigned ua = __float_as_uint(a), ub = __float_as_uint(b);
  unsigned ha = (ua + 0x8000u) & 0xffff0000u;
  unsigned hb = (ub + 0x8000u) & 0xffff0000u;
  float la = a - __uint_as_float(ha);
  float lb = b - __uint_as_float(hb);
  hp = (ha >> 16) | hb;
  lp = (__float_as_uint(la) >> 16) | (__float_as_uint(lb) & 0xffff0000u);
}

// async global -> LDS, 16B per lane. LDS dest: wave-uniform base + lane*16.
// Global src: per-lane (carries the swizzle). Drained by __syncthreads (vmcnt0).
__device__ __forceinline__ void gl2l(const unsigned short* g, unsigned short* l) {
  __builtin_amdgcn_global_load_lds(
      (const __attribute__((address_space(1))) void*)g,
      (__attribute__((address_space(3))) void*)l, 16, 0, 0);
}

union U8 { unsigned u[4]; short8 s; };

__global__ __launch_bounds__(256) void sentinel_kernel(float* __restrict__ out, int n, float v) {
  int i = blockIdx.x * 256 + threadIdx.x;
  if (i < n) out[i] = v;
}

// ---------------- BatchNorm stats ----------------
__global__ __launch_bounds__(256) void bn_stats_kernel(
    const float* __restrict__ tok, const float* __restrict__ g,
    const float* __restrict__ bb, float* __restrict__ ss) {
  __shared__ float red[256];
  const int d = blockIdx.x;
  float sum = 0.f, sumsq = 0.f;
  for (int s = threadIdx.x; s < 4096; s += 256) {
    float v = tok[s * 64 + d];
    sum += v; sumsq += v * v;
  }
  sum = block_reduce(sum, red);
  sumsq = block_reduce(sumsq, red);
  if (threadIdx.x == 0) {
    float mu = sum * (1.f / 4096.f);
    float var = sumsq * (1.f / 4096.f) - mu * mu;
    float sc = g[d] * rsqrtf(fmaxf(var, 0.f) + 1e-5f);
    ss[d] = sc;
    ss[64 + d] = bb[d] - mu * sc;
  }
}

__global__ __launch_bounds__(256) void tn_kernel(
    const float* __restrict__ tok, const float* __restrict__ ss,
    float* __restrict__ tn) {
  int idx = blockIdx.x * 256 + threadIdx.x;
  int d = idx & 63;
  tn[idx] = tok[idx] * ss[d] + ss[64 + d];
}

__global__ __launch_bounds__(256) void reverse_kernel(
    const float* __restrict__ x0, float* __restrict__ x0r) {
  int idx = blockIdx.x * 256 + threadIdx.x;
  int row = idx >> 9, e = idx & 511;
  int b = row >> 10, t = row & 1023;
  x0r[idx] = x0[((size_t)((b << 10) + (1023 - t))) * 512 + e];
}

// ---------------- row LayerNorm, f32 out (N = 512 or 256) ----------------
__global__ __launch_bounds__(256) void ln_kernel(
    const float* __restrict__ x, const float* __restrict__ g,
    const float* __restrict__ b, float* __restrict__ out, int N) {
  __shared__ float red[256];
  const size_t r = blockIdx.x;
  const int tid = threadIdx.x;
  float v0 = x[r * N + tid];
  float v1 = (N > 256) ? x[r * N + 256 + tid] : 0.f;
  float sum = block_reduce(v0 + v1, red);
  float sumsq = block_reduce(v0 * v0 + v1 * v1, red);
  float mean = sum / (float)N;
  float var = sumsq / (float)N - mean * mean;
  float rs = rsqrtf(fmaxf(var, 0.f) + 1e-5f);
  out[r * N + tid] = (v0 - mean) * rs * g[tid] + b[tid];
  if (N > 256)
    out[r * N + 256 + tid] = (v1 - mean) * rs * g[256 + tid] + b[256 + tid];
}

// ---------------- row LayerNorm, N=512, bf16 hi/lo plane out ----------------
// Wave-per-row (2 rows/wave, 8 rows/block): shfl reduction, zero barriers.
__global__ __launch_bounds__(256) void ln_pl(
    const float* __restrict__ x, const float* __restrict__ g,
    const float* __restrict__ b, unsigned short* __restrict__ oh,
    unsigned short* __restrict__ ol) {
  const int w = threadIdx.x >> 6, lane = threadIdx.x & 63;
  const int c0 = lane * 8;
  float4 g0 = *reinterpret_cast<const float4*>(g + c0);
  float4 g1 = *reinterpret_cast<const float4*>(g + c0 + 4);
  float4 b0 = *reinterpret_cast<const float4*>(b + c0);
  float4 b1 = *reinterpret_cast<const float4*>(b + c0 + 4);
  const float gv[8] = {g0.x, g0.y, g0.z, g0.w, g1.x, g1.y, g1.z, g1.w};
  const float bv[8] = {b0.x, b0.y, b0.z, b0.w, b1.x, b1.y, b1.z, b1.w};
#pragma unroll
  for (int rr = 0; rr < 2; ++rr) {
    size_t r = (size_t)blockIdx.x * 8 + w * 2 + rr;
    const float* xp = x + r * 512 + c0;
    float4 a0 = *reinterpret_cast<const float4*>(xp);
    float4 a1 = *reinterpret_cast<const float4*>(xp + 4);
    const float av[8] = {a0.x, a0.y, a0.z, a0.w, a1.x, a1.y, a1.z, a1.w};
    float s = 0.f, q = 0.f;
#pragma unroll
    for (int j = 0; j < 8; ++j) { s += av[j]; q += av[j] * av[j]; }
#pragma unroll
    for (int off = 32; off >= 1; off >>= 1) {
      s += __shfl_xor(s, off);
      q += __shfl_xor(q, off);
    }
    float mean = s * (1.f / 512.f);
    float var = q * (1.f / 512.f) - mean * mean;
    float rs = rsqrtf(fmaxf(var, 0.f) + 1e-5f);
    unsigned short hv[8], lv[8];
#pragma unroll
    for (int j = 0; j < 8; ++j) {
      float o = (av[j] - mean) * rs * gv[j] + bv[j];
      cvt1(o, hv[j], lv[j]);
    }
    uint4 hq = make_uint4(hv[0] | ((unsigned)hv[1] << 16), hv[2] | ((unsigned)hv[3] << 16),
                          hv[4] | ((unsigned)hv[5] << 16), hv[6] | ((unsigned)hv[7] << 16));
    uint4 lq = make_uint4(lv[0] | ((unsigned)lv[1] << 16), lv[2] | ((unsigned)lv[3] << 16),
                          lv[4] | ((unsigned)lv[5] << 16), lv[6] | ((unsigned)lv[7] << 16));
    *reinterpret_cast<uint4*>(oh + r * 512 + c0) = hq;
    *reinterpret_cast<uint4*>(ol + r * 512 + c0) = lq;
  }
}

// ---------------- weight conversion: f32 [K][N] -> transposed planes [N][K] ----------------
__global__ __launch_bounds__(256) void convw(
    const float* __restrict__ W, unsigned short* __restrict__ hi,
    unsigned short* __restrict__ lo, int K, int N, long dls) {
  int id = blockIdx.x * 256 + threadIdx.x;
  int total = (K >> 3) * N;
  if (id >= total) return;
  int c = id / N, n = id - c * N;
  const float* Wp = W + (size_t)blockIdx.y * K * N;
  size_t doff = (size_t)blockIdx.y * dls + (size_t)n * K + c * 8;
  unsigned short h8[8], l8[8];
#pragma unroll
  for (int j = 0; j < 8; ++j) {
    float xv = Wp[(size_t)(c * 8 + j) * N + n];
    cvt1(xv, h8[j], l8[j]);
  }
  uint4 hv = make_uint4(h8[0] | ((unsigned)h8[1] << 16), h8[2] | ((unsigned)h8[3] << 16),
                        h8[4] | ((unsigned)h8[5] << 16), h8[6] | ((unsigned)h8[7] << 16));
  uint4 lv = make_uint4(l8[0] | ((unsigned)l8[1] << 16), l8[2] | ((unsigned)l8[3] << 16),
                        l8[4] | ((unsigned)l8[5] << 16), l8[6] | ((unsigned)l8[7] << 16));
  *reinterpret_cast<uint4*>(hi + doff) = hv;
  *reinterpret_cast<uint4*>(lo + doff) = lv;
}

// --------- small GEMM (f32): out[M,N] = A@W + bias (act) ---------
#define BK 16
template <int ACT>  // 0 none, 1 gelu(exact), 2 tanh
__global__ __launch_bounds__(256) void gemm3(
    const float* __restrict__ A, const float* __restrict__ W,
    const float* __restrict__ bias, const float* resid,
    float* out, int M, int N, int K) {
  __shared__ float As[BK][64 + 4];
  __shared__ float Bs[BK][64 + 4];
  const int tid = threadIdx.x;
  const int tx = tid & 15, ty = tid >> 4;
  const int n0 = blockIdx.x * 64, m0 = blockIdx.y * 64;
  float acc[4][4] = {};
  for (int k0 = 0; k0 < K; k0 += BK) {
    {
      int m = tid >> 2, kq = tid & 3;
      float4 a4 = *reinterpret_cast<const float4*>(A + (size_t)(m0 + m) * K + k0 + kq * 4);
      As[kq * 4 + 0][m] = a4.x; As[kq * 4 + 1][m] = a4.y;
      As[kq * 4 + 2][m] = a4.z; As[kq * 4 + 3][m] = a4.w;
    }
    {
      int kk = tid >> 4, nq = tid & 15;
      float4 b4 = *reinterpret_cast<const float4*>(W + (size_t)(k0 + kk) * N + n0 + nq * 4);
      Bs[kk][nq * 4 + 0] = b4.x; Bs[kk][nq * 4 + 1] = b4.y;
      Bs[kk][nq * 4 + 2] = b4.z; Bs[kk][nq * 4 + 3] = b4.w;
    }
    __syncthreads();
#pragma unroll
    for (int kq = 0; kq < BK; ++kq) {
      float4 av = *reinterpret_cast<const float4*>(&As[kq][ty * 4]);
      float4 bv = *reinterpret_cast<const float4*>(&Bs[kq][tx * 4]);
      acc[0][0] += av.x * bv.x; acc[0][1] += av.x * bv.y; acc[0][2] += av.x * bv.z; acc[0][3] += av.x * bv.w;
      acc[1][0] += av.y * bv.x; acc[1][1] += av.y * bv.y; acc[1][2] += av.y * bv.z; acc[1][3] += av.y * bv.w;
      acc[2][0] += av.z * bv.x; acc[2][1] += av.z * bv.y; acc[2][2] += av.z * bv.z; acc[2][3] += av.z * bv.w;
      acc[3][0] += av.w * bv.x; acc[3][1] += av.w * bv.y; acc[3][2] += av.w * bv.z; acc[3][3] += av.w * bv.w;
    }
    __syncthreads();
  }
#pragma unroll
  for (int i = 0; i < 4; ++i) {
    int m = m0 + ty * 4 + i;
#pragma unroll
    for (int j = 0; j < 4; ++j) {
      int n = n0 + tx * 4 + j;
      float v = acc[i][j] + bias[n];
      if (resid) v += resid[(size_t)m * N + n];
      if (ACT == 1) v = 0.5f * v * (1.f + erff(v * 0.70710678118654752f));
      if (ACT == 2) v = tanhf(v);
      out[(size_t)m * N + n] = v;
    }
  }
}

// --------- MFMA GEMM over pre-split bf16 planes. 128x128x32 tiles, 4 waves. ---------
// Staging via global_load_lds (16B/lane) into double-buffered LDS; one barrier per
// K-step. Wave w owns plane w (0=Ah 1=Al 2=Bh 3=Bl). XOR slot swizzle carried on
// the per-lane global address; LDS linear; frag ds_read_b128 conflict-free.
// ACT: 0 none, 1 gelu, 2 tanh. OUTMODE: 0 f32, 1 planes, 2 both.
// ATOMIC: f32 atomicAdd into Cf (bias added by z==0). BIAS3: b0/b1/b2 512-wide sections.
// QKV: attention epilogue — Q cols (n0<512): planes scaled 1/8; K cols: planes;
//      V cols (n0>=1024): transposed vT planes [b][h][d][token] (uint2-packed).
template <int ACT, int OUTMODE, int ATOMIC, int BIAS3, int QKV>
__global__ __launch_bounds__(256, 2) void gemm_bf(
    const unsigned short* __restrict__ Ahp, const unsigned short* __restrict__ Alp,
    const unsigned short* __restrict__ Bhp, const unsigned short* __restrict__ Blp,
    const float* __restrict__ b0, const float* __restrict__ b1, const float* __restrict__ b2,
    float* __restrict__ Cf, unsigned short* __restrict__ Chp, unsigned short* __restrict__ Clp,
    unsigned short* __restrict__ vth, unsigned short* __restrict__ vtl,
    int M, int N, int K, int KZ) {
  // [buf][plane][row][32 ushorts]: 2 x 32KB
  __shared__ __align__(16) unsigned short LDS[2][4][128][32];
  const int tid = threadIdx.x;
  const int lane = tid & 63, wid = tid >> 6;
  const int wr = wid >> 1, wc = wid & 1;
  const int lr = lane & 15, lq = lane >> 4;

  // XCD swizzle over (x,y)
  const int gx = gridDim.x;
  int lin = blockIdx.y * gx + blockIdx.x;
  int qch = (gx * gridDim.y) >> 3;
  int swz = (lin & 7) * qch + (lin >> 3);
  const int nb = swz % gx, mb = swz / gx;
  const int n0 = nb * 128, m0 = mb * 128;
  const int kbase = blockIdx.z * KZ, kend = kbase + KZ;

  f32x4 acc[4][4];
#pragma unroll
  for (int i = 0; i < 4; ++i)
#pragma unroll
    for (int j = 0; j < 4; ++j) { acc[i][j][0] = 0.f; acc[i][j][1] = 0.f; acc[i][j][2] = 0.f; acc[i][j][3] = 0.f; }

  // wave wid stages plane wid
  const unsigned short* gplane =
      (wid == 0) ? Ahp + (size_t)m0 * K :
      (wid == 1) ? Alp + (size_t)m0 * K :
      (wid == 2) ? Bhp + (size_t)n0 * K : Blp + (size_t)n0 * K;
  const int srow = lane >> 2;   // 0..15 within a 16-row chunk
  const int sphys = lane & 3;   // physical 16B slot

  auto stage = [&](int buf, int k0) {
#pragma unroll
    for (int j = 0; j < 8; ++j) {
      int row = j * 16 + srow;
      int logslot = sphys ^ ((row >> 1) & 3);
      gl2l(gplane + (size_t)row * K + k0 + logslot * 8, &LDS[buf][wid][j * 16][0]);
    }
  };

  stage(0, kbase);
  __syncthreads();
  int cur = 0;
  for (int k0 = kbase; k0 < kend; k0 += 32) {
    if (k0 + 32 < kend) stage(cur ^ 1, k0 + 32);
    short8 ah[4], al[4], bh[4], bl[4];
#pragma unroll
    for (int mi = 0; mi < 4; ++mi) {
      int row = wr * 64 + mi * 16 + lr;
      int off = (lq ^ ((row >> 1) & 3)) * 8;
      ah[mi] = *reinterpret_cast<const short8*>(&LDS[cur][0][row][off]);
      al[mi] = *reinterpret_cast<const short8*>(&LDS[cur][1][row][off]);
    }
#pragma unroll
    for (int ni = 0; ni < 4; ++ni) {
      int n = wc * 64 + ni * 16 + lr;
      int off = (lq ^ ((n >> 1) & 3)) * 8;
      bh[ni] = *reinterpret_cast<const short8*>(&LDS[cur][2][n][off]);
      bl[ni] = *reinterpret_cast<const short8*>(&LDS[cur][3][n][off]);
    }
#pragma unroll
    for (int mi = 0; mi < 4; ++mi)
#pragma unroll
      for (int ni = 0; ni < 4; ++ni) {
        acc[mi][ni] = __builtin_amdgcn_mfma_f32_16x16x32_bf16(ah[mi], bh[ni], acc[mi][ni], 0, 0, 0);
        acc[mi][ni] = __builtin_amdgcn_mfma_f32_16x16x32_bf16(ah[mi], bl[ni], acc[mi][ni], 0, 0, 0);
        acc[mi][ni] = __builtin_amdgcn_mfma_f32_16x16x32_bf16(al[mi], bh[ni], acc[mi][ni], 0, 0, 0);
      }
    __syncthreads();   // drains prefetch (vmcnt0) + frees cur for next stage
    cur ^= 1;
  }

  // ---- epilogue ----
  if (QKV) {
    const float* bsec = (n0 < 512) ? b0 : (n0 < 1024 ? b1 : b2);
    const int bof = (n0 & 511) - n0;
    if (n0 < 1024) {     // Q (scaled 1/8) and K sections -> planes [token][1536]
      const float scale = (n0 < 512) ? 0.125f : 1.f;
#pragma unroll
      for (int mi = 0; mi < 4; ++mi)
#pragma unroll
        for (int r = 0; r < 4; ++r) {
          int grow = m0 + wr * 64 + mi * 16 + lq * 4 + r;
#pragma unroll
          for (int ni = 0; ni < 4; ++ni) {
            int col = n0 + wc * 64 + ni * 16 + lr;
            float v = (acc[mi][ni][r] + bsec[col + bof]) * scale;
            unsigned short hv, lv;
            cvt1(v, hv, lv);
            Chp[(size_t)grow * N + col] = hv;
            Clp[(size_t)grow * N + col] = lv;
          }
        }
    } else {             // V section -> transposed vT planes [b][h][d][token]
#pragma unroll
      for (int mi = 0; mi < 4; ++mi) {
        int t0 = m0 + wr * 64 + mi * 16 + lq * 4;
        int bb = t0 >> 10, tt = t0 & 1023;
#pragma unroll
        for (int ni = 0; ni < 4; ++ni) {
          int col = n0 + wc * 64 + ni * 16 + lr;
          float bias = bsec[col + bof];
          int hh_ = (col - 1024) >> 6, dd = (col - 1024) & 63;
          unsigned short h4[4], l4[4];
#pragma unroll
          for (int r = 0; r < 4; ++r) cvt1(acc[mi][ni][r] + bias, h4[r], l4[r]);
          size_t off = ((size_t)((bb * 8 + hh_) * 64 + dd)) * 1024 + tt;
          *reinterpret_cast<uint2*>(vth + off) = make_uint2(
              h4[0] | ((unsigned)h4[1] << 16), h4[2] | ((unsigned)h4[3] << 16));
          *reinterpret_cast<uint2*>(vtl + off) = make_uint2(
              l4[0] | ((unsigned)l4[1] << 16), l4[2] | ((unsigned)l4[3] << 16));
        }
      }
    }
    return;
  }
  const float* bsec = b0;
  int bof = 0;
  if (BIAS3) { bsec = (n0 < 512) ? b0 : (n0 < 1024 ? b1 : b2); bof = (n0 & 511) - n0; }
#pragma unroll
  for (int mi = 0; mi < 4; ++mi) {
#pragma unroll
    for (int r = 0; r < 4; ++r) {
      int grow = m0 + wr * 64 + mi * 16 + lq * 4 + r;
#pragma unroll
      for (int ni = 0; ni < 4; ++ni) {
        int col = n0 + wc * 64 + ni * 16 + lr;
        float v = acc[mi][ni][r];
        float bias = BIAS3 ? bsec[col + bof] : b0[col];
        if (ATOMIC) {
          if (blockIdx.z == 0) v += bias;
          atomicAdd(&Cf[(size_t)grow * N + col], v);
        } else {
          v += bias;
          if (ACT == 1) v = 0.5f * v * (1.f + erff(v * 0.70710678118654752f));
          if (ACT == 2) v = tanhf(v);
          if (OUTMODE == 0 || OUTMODE == 2) Cf[(size_t)grow * N + col] = v;
          if (OUTMODE >= 1) {
            unsigned short hv, lv;
            cvt1(v, hv, lv);
            Chp[(size_t)grow * N + col] = hv;
            Clp[(size_t)grow * N + col] = lv;
          }
        }
      }
    }
  }
}

// ---------------- attention: MFMA flash over pre-split planes, pipelined ----------------
// K tile double-buffered (prefetch issued at loop top, drained at the mid barrier);
// V single-buffered but staged at loop top so its latency hides under QK^T+softmax.
// 2 barriers/step. Mask read per-lane from global (no km LDS). Q staged into the
// PU region in the prologue (concurrent with the K(0) prefetch).
__global__ __launch_bounds__(256, 2) void attn_mfma(
    const unsigned short* __restrict__ qkvh, const unsigned short* __restrict__ qkvl,
    const unsigned short* __restrict__ vth, const unsigned short* __restrict__ vtl,
    const float* __restrict__ mask,
    unsigned short* __restrict__ ybh, unsigned short* __restrict__ ybl, int rev) {
  __shared__ __align__(16) unsigned short KB[2][2][4096];  // [buf][hi/lo] K tiles
  __shared__ __align__(16) unsigned short VB[2][4096];     // [hi/lo] V^T tile
  __shared__ __align__(16) float PU[64 * 68];              // P f32; prologue: Q planes

  const int tid = threadIdx.x;
  const int lane = tid & 63, w = tid >> 6;
  const int lr = lane & 15, lq = lane >> 4;

  const int id = blockIdx.x;          // complementary-pair mapping
  const int top = id >> 8;
  const int r5 = id & 255;
  const int qt = top ? (15 - (r5 >> 4)) : (r5 >> 4);
  const int bh_ = (r5 & 15) | (top << 4);
  const int b = bh_ >> 3, h = bh_ & 7;

  // per-wave staging helpers (wave-uniform branch conditions)
  const int srow = lane >> 3, sp = lane & 7;     // chunk coords: row=j*8+srow, slot
  auto stageK = [&](int buf, int kt2) {          // waves 0,1 (hi,lo)
    const unsigned short* src = (w == 0) ? qkvh : qkvl;
    unsigned short* dst = &KB[buf][w][0];
#pragma unroll
    for (int j = 0; j < 8; ++j) {
      int row = j * 8 + srow;
      int slot = sp ^ (row & 7);
      gl2l(src + (size_t)(b * 1024 + kt2 * 64 + row) * 1536 + 512 + h * 64 + slot * 8,
           dst + j * 512);
    }
  };
  auto stageV = [&](int kt2) {                   // waves 2,3 (hi,lo)
    const unsigned short* src = (w == 2) ? vth : vtl;
    unsigned short* dst = &VB[w - 2][0];
#pragma unroll
    for (int j = 0; j < 8; ++j) {
      int row = j * 8 + srow;                    // row = d 0..63
      int slot = sp ^ (row & 7);
      gl2l(src + (size_t)((b * 8 + h) * 64 + row) * 1024 + kt2 * 64 + slot * 8,
           dst + j * 512);
    }
  };

  // ---- prologue: stage Q planes into the PU region + prefetch K(0) ----
  unsigned short* QS = reinterpret_cast<unsigned short*>(PU);
  {
    const unsigned short* src = (w < 2) ? qkvh : qkvl;
    unsigned short* dst = QS + (w >> 1) * 4096;
    int half = w & 1;
#pragma unroll
    for (int j = 0; j < 4; ++j) {
      int chunk = half * 256 + j * 64 + lane;
      int row = chunk >> 3, p = chunk & 7;
      int slot = p ^ (row & 7);
      gl2l(src + (size_t)(b * 1024 + qt * 64 + row) * 1536 + h * 64 + slot * 8,
           dst + (half * 256 + j * 64) * 8);
    }
  }
  if (w < 2) stageK(0, 0);
  __syncthreads();
  short8 qa_h[2], qa_l[2];
#pragma unroll
  for (int ks = 0; ks < 2; ++ks) {
    int row = w * 16 + lr;
    int phys = (lq + ks * 4) ^ (row & 7);
    qa_h[ks] = *reinterpret_cast<const short8*>(&QS[row * 64 + phys * 8]);
    qa_l[ks] = *reinterpret_cast<const short8*>(&QS[4096 + row * 64 + phys * 8]);
  }
  __syncthreads();  // PU region now free for P writes

  float m_[4], l_[4] = {0.f, 0.f, 0.f, 0.f};
  f32x4 o_[4];
#pragma unroll
  for (int r = 0; r < 4; ++r) m_[r] = -1e30f;
#pragma unroll
  for (int df = 0; df < 4; ++df) { o_[df][0] = 0.f; o_[df][1] = 0.f; o_[df][2] = 0.f; o_[df][3] = 0.f; }

  int cur = 0;
  for (int kt = 0; kt <= qt; ++kt) {
    // ---- issue prefetch/stage (async, drained at the mid barrier) ----
    if (w < 2) { if (kt < qt) stageK(cur ^ 1, kt + 1); }
    else stageV(kt);
    // mask values (per-lane, global; L1/L2 cached broadcast)
    float kmv[4];
#pragma unroll
    for (int kf = 0; kf < 4; ++kf) {
      int s = kt * 64 + kf * 16 + lr;
      kmv[kf] = mask[b * 1024 + (rev ? (1023 - s) : s)];
    }

    // ---- S = Q K^T (x3 MFMA) from KB[cur] ----
    f32x4 sacc[4];
#pragma unroll
    for (int kf = 0; kf < 4; ++kf) { sacc[kf][0] = 0.f; sacc[kf][1] = 0.f; sacc[kf][2] = 0.f; sacc[kf][3] = 0.f; }
#pragma unroll
    for (int ks = 0; ks < 2; ++ks) {
#pragma unroll
      for (int kf = 0; kf < 4; ++kf) {
        int col = kf * 16 + lr;
        int phys = (lq + ks * 4) ^ (lr & 7);
        short8 kbh = *reinterpret_cast<const short8*>(&KB[cur][0][col * 64 + phys * 8]);
        short8 kbl = *reinterpret_cast<const short8*>(&KB[cur][1][col * 64 + phys * 8]);
        sacc[kf] = __builtin_amdgcn_mfma_f32_16x16x32_bf16(qa_h[ks], kbh, sacc[kf], 0, 0, 0);
        sacc[kf] = __builtin_amdgcn_mfma_f32_16x16x32_bf16(qa_h[ks], kbl, sacc[kf], 0, 0, 0);
        sacc[kf] = __builtin_amdgcn_mfma_f32_16x16x32_bf16(qa_l[ks], kbh, sacc[kf], 0, 0, 0);
      }
    }

    // ---- online softmax in registers ----
    const bool diag = (kt == qt);
#pragma unroll
    for (int r = 0; r < 4; ++r) {
      int fi = (w * 16 + lq * 4 + r) >> 3;
      float mt = -1e30f;
#pragma unroll
      for (int kf = 0; kf < 4; ++kf) {
        int key = kf * 16 + lr;
        bool ok = (kmv[kf] > 0.f) && (!diag || ((key >> 3) <= fi));
        float x = ok ? sacc[kf][r] : -1e30f;
        sacc[kf][r] = x;
        mt = fmaxf(mt, x);
      }
      mt = fmaxf(mt, __shfl_xor(mt, 1, 16));
      mt = fmaxf(mt, __shfl_xor(mt, 2, 16));
      mt = fmaxf(mt, __shfl_xor(mt, 4, 16));
      mt = fmaxf(mt, __shfl_xor(mt, 8, 16));
      float mn = fmaxf(m_[r], mt);
      float al = __expf(m_[r] - mn);
      m_[r] = mn;
      float rs = 0.f;
#pragma unroll
      for (int kf = 0; kf < 4; ++kf) {
        float sv = sacc[kf][r];
        float p = (sv > -1e29f) ? __expf(sv - mn) : 0.f;
        sacc[kf][r] = p;
        rs += p;
      }
      rs += __shfl_xor(rs, 1, 16);
      rs += __shfl_xor(rs, 2, 16);
      rs += __shfl_xor(rs, 4, 16);
      rs += __shfl_xor(rs, 8, 16);
      l_[r] = l_[r] * al + rs;
#pragma unroll
      for (int df = 0; df < 4; ++df) o_[df][r] *= al;
    }
    // ---- write P (f32, 68-stride) ----
#pragma unroll
    for (int kf = 0; kf < 4; ++kf)
#pragma unroll
      for (int r = 0; r < 4; ++r)
        PU[(w * 16 + lq * 4 + r) * 68 + kf * 16 + lr] = sacc[kf][r];
    __syncthreads();  // publishes PU; drains K-prefetch + V-stage

    // ---- O += P V (x3 MFMA) ----
#pragma unroll
    for (int ks = 0; ks < 2; ++ks) {
      const float* pp = &PU[(w * 16 + lr) * 68 + ks * 32 + lq * 8];
      float4 p0 = *reinterpret_cast<const float4*>(pp);
      float4 p1 = *reinterpret_cast<const float4*>(pp + 4);
      U8 th, tl;
      cvt2(p0.x, p0.y, th.u[0], tl.u[0]);
      cvt2(p0.z, p0.w, th.u[1], tl.u[1]);
      cvt2(p1.x, p1.y, th.u[2], tl.u[2]);
      cvt2(p1.z, p1.w, th.u[3], tl.u[3]);
      short8 pa_h = th.s, pa_l = tl.s;
#pragma unroll
      for (int df = 0; df < 4; ++df) {
        int col = df * 16 + lr;
        int phys = (lq + ks * 4) ^ (lr & 7);
        short8 vbh = *reinterpret_cast<const short8*>(&VB[0][col * 64 + phys * 8]);
        short8 vbl = *reinterpret_cast<const short8*>(&VB[1][col * 64 + phys * 8]);
        o_[df] = __builtin_amdgcn_mfma_f32_16x16x32_bf16(pa_h, vbh, o_[df], 0, 0, 0);
        o_[df] = __builtin_amdgcn_mfma_f32_16x16x32_bf16(pa_h, vbl, o_[df], 0, 0, 0);
        o_[df] = __builtin_amdgcn_mfma_f32_16x16x32_bf16(pa_l, vbh, o_[df], 0, 0, 0);
      }
    }
    __syncthreads();  // all reads of PU/VB/KB[cur] done before next-step overwrites
    cur ^= 1;
  }

  // ---- normalize + write planes ----
#pragma unroll
  for (int r = 0; r < 4; ++r) {
    float inv = 1.f / fmaxf(l_[r], 1e-30f);
    int qrow = qt * 64 + w * 16 + lq * 4 + r;
#pragma unroll
    for (int df = 0; df < 4; ++df) {
      float val = o_[df][r] * inv;
      unsigned short hv, lv;
      cvt1(val, hv, lv);
      size_t idx = (size_t)(b * 1024 + qrow) * 512 + h * 64 + df * 16 + lr;
      ybh[idx] = hv; ybl[idx] = lv;
    }
  }
}

// ---------------- frame mean (+ FLOAT32 output write) ----------------
__global__ __launch_bounds__(256) void frame_mean_kernel(
    const float* __restrict__ xo, float* __restrict__ xf,
    float* __restrict__ outf) {
  int row = blockIdx.x;       // b*128+tf
  int o = threadIdx.x;
  float s = 0.f;
#pragma unroll
  for (int c = 0; c < 8; ++c) s += xo[((size_t)row * 8 + c) * 256 + o];
  s *= 0.125f;
  xf[row * 256 + o] = s;
  if (outf) outf[row * 256 + o] = s;
}

// ---------------- losses ----------------
__global__ __launch_bounds__(256) void loss_reg_kernel(
    const float* __restrict__ pd, const float* __restrict__ tok,
    const float* __restrict__ mask, float* __restrict__ acc, int rev) {
  __shared__ float red[256];
  float local = 0.f;
  for (int idx = blockIdx.x * 256 + threadIdx.x; idx < 260096; idx += gridDim.x * 256) {
    int b = idx / 65024, r2 = idx % 65024;
    int t = r2 >> 6, d = r2 & 63;
    float pred = pd[((size_t)((b << 10) + t)) * 64 + d] * mask[(b << 10) + t];
    int tt = rev ? (1015 - t) : (t + 8);
    float tgt = tok[((size_t)((b << 10) + tt)) * 64 + d] * mask[(b << 10) + tt];
    float df = pred - tgt;
    local += df * df;
  }
  float s = block_reduce(local, red);
  if (threadIdx.x == 0) atomicAdd(acc, s);
}

__global__ __launch_bounds__(256) void loss_fr_kernel(
    const float* __restrict__ pf, const float* __restrict__ tok,
    const float* __restrict__ mask, float* __restrict__ acc, int rev) {
  __shared__ float red[256];
  float local = 0.f;
  for (int idx = blockIdx.x * 256 + threadIdx.x; idx < 260096; idx += gridDim.x * 256) {
    int b = idx / 65024, r2 = idx % 65024;
    int i = r2 >> 9, u = r2 & 511;
    float pred = pf[((size_t)(b * 128 + i)) * 512 + u];
    int c = u >> 6;
    int t = rev ? ((126 - i) * 8 + c) : ((i + 1) * 8 + c);
    float tgt = tok[((size_t)((b << 10) + t)) * 64 + (u & 63)] * mask[(b << 10) + t];
    float df = pred - tgt;
    local += df * df;
  }
  float s = block_reduce(local, red);
  if (threadIdx.x == 0) atomicAdd(acc, s);
}

__global__ void finalize_kernel(const float* __restrict__ acc, float* __restrict__ out) {
  int i = threadIdx.x;
  if (i < 4) out[131072 + i] = acc[i] * (1.0f / 260096.0f);
}

extern "C" void kernel_launch(void* const* d_in, const int* in_sizes, int n_in,
                              void* d_out, int out_size, void* d_ws, size_t ws_size,
                              hipStream_t stream) {
  float* ws = (float*)d_ws;
  const size_t OFF_SS   = 0;
  const size_t OFF_LACC = 128;
  const size_t OFF_TN   = 256;
  const size_t OFF_X0   = 262400;
  const size_t OFF_X0R  = 2359552;
  const size_t OFF_X    = 4456704;
  const size_t OFF_HPL  = 6553856;    // h planes (hi/lo)
  const size_t OFF_QKV  = 8651008;    // qkv planes (hi 3145728 fl, lo 3145728 fl); u planes alias
  const size_t OFF_YB   = 14942464;   // yb planes 2097152 fl
  const size_t OFF_XO   = 17039616;   // f32 1048576
  const size_t OFF_XOPL = 18088192;   // xo planes 1048576 fl
  const size_t OFF_HD   = 19136768;
  const size_t OFF_HD2  = 20185344;
  const size_t OFF_PD   = 21233920;
  const size_t OFF_XF   = 21496064;
  const size_t OFF_HF   = 21627136;
  const size_t OFF_HF2  = 21758208;
  const size_t OFF_PF   = 21889280;
  const size_t OFF_VT   = 22151424;   // vT planes 2097152 fl
  const size_t OFF_WB   = 24248576;
  const size_t TOTAL_MIN = OFF_WB + 1048576;    // JIT scratch mode (~101 MB)
  const size_t TOTAL_BIG = OFF_WB + 19070976;   // full weight-plane mode (~173 MB)

  float* ss   = ws + OFF_SS;
  float* lacc = ws + OFF_LACC;
  float* tn   = ws + OFF_TN;
  float* x0   = ws + OFF_X0;
  float* x0r  = ws + OFF_X0R;
  float* x    = ws + OFF_X;
  unsigned short* hh = (unsigned short*)(ws + OFF_HPL);
  unsigned short* hl = hh + 2097152;
  unsigned short* qkvh = (unsigned short*)(ws + OFF_QKV);
  unsigned short* qkvl = qkvh + 6291456;
  unsigned short* uh = (unsigned short*)(ws + OFF_QKV);   // alias (MLP phase only)
  unsigned short* ul = uh + 8388608;
  unsigned short* ybh = (unsigned short*)(ws + OFF_YB);
  unsigned short* ybl = ybh + 2097152;
  float* xo   = ws + OFF_XO;
  unsigned short* xoh = (unsigned short*)(ws + OFF_XOPL);
  unsigned short* xol = xoh + 1048576;
  float* hd   = ws + OFF_HD;
  float* hd2  = ws + OFF_HD2;
  float* pd   = ws + OFF_PD;
  float* xf   = ws + OFF_XF;
  float* hf   = ws + OFF_HF;
  float* hf2  = ws + OFF_HF2;
  float* pf   = ws + OFF_PF;
  unsigned short* vth = (unsigned short*)(ws + OFF_VT);
  unsigned short* vtl = vth + 2097152;
  unsigned short* wb16 = (unsigned short*)(ws + OFF_WB);
  float* out_f = (float*)d_out;   // OUTPUT IS FLOAT32

  static const int EXPECTED[39] = {
      262144, 4096, 4096, 64, 64, 32768, 512, 3072, 3072, 3072, 3072,
      1572864, 3072, 1572864, 3072, 1572864, 3072, 1572864, 3072,
      6291456, 12288, 6291456, 3072, 512, 512, 131072, 256, 65536, 256,
      256, 256, 16384, 64, 65536, 256, 256, 256, 131072, 512};
  bool manifest_ok = (n_in == 39) && (ws_size >= TOTAL_MIN * sizeof(float));
  if (manifest_ok)
    for (int i = 0; i < 39; ++i)
      if (in_sizes[i] != EXPECTED[i]) { manifest_ok = false; break; }
  if (!manifest_ok) {
    hipLaunchKernelGGL(sentinel_kernel, dim3((out_size + 255) / 256), dim3(256), 0, stream,
                       out_f, out_size, 2000.0f);
    return;
  }
  const bool bigws = ws_size >= TOTAL_BIG * sizeof(float);

  const float* tok    = (const float*)d_in[0];
  const float* mask   = (const float*)d_in[2];
  const float* bn_g   = (const float*)d_in[3];
  const float* bn_b   = (const float*)d_in[4];
  const float* We     = (const float*)d_in[5];
  const float* be     = (const float*)d_in[6];
  const float* ln1_g  = (const float*)d_in[7];
  const float* ln1_b  = (const float*)d_in[8];
  const float* ln2_g  = (const float*)d_in[9];
  const float* ln2_b  = (const float*)d_in[10];
  const float* Wq     = (const float*)d_in[11];
  const float* bq     = (const float*)d_in[12];
  const float* Wk     = (const float*)d_in[13];
  const float* bk     = (const float*)d_in[14];
  const float* Wv     = (const float*)d_in[15];
  const float* bv     = (const float*)d_in[16];
  const float* Wo     = (const float*)d_in[17];
  const float* bo     = (const float*)d_in[18];
  const float* W1     = (const float*)d_in[19];
  const float* b1     = (const float*)d_in[20];
  const float* W2     = (const float*)d_in[21];
  const float* b2     = (const float*)d_in[22];
  const float* lnf_g  = (const float*)d_in[23];
  const float* lnf_b  = (const float*)d_in[24];
  const float* Wp     = (const float*)d_in[25];
  const float* bp     = (const float*)d_in[26];
  const float* Wd1    = (const float*)d_in[27];
  const float* bd1    = (const float*)d_in[28];
  const float* lnd_g  = (const float*)d_in[29];
  const float* lnd_b  = (const float*)d_in[30];
  const float* Wd2    = (const float*)d_in[31];
  const float* bd2    = (const float*)d_in[32];
  const float* Wf1    = (const float*)d_in[33];
  const float* bf1    = (const float*)d_in[34];
  const float* lnfr_g = (const float*)d_in[35];
  const float* lnfr_b = (const float*)d_in[36];
  const float* Wf2    = (const float*)d_in[37];
  const float* bf2    = (const float*)d_in[38];

  // weight-plane pointers (big mode), ushort offsets
  unsigned short* wqkv_h = wb16;
  unsigned short* wqkv_l = wb16 + 4718592;
  unsigned short* wo_h   = wb16 + 9437184;
  unsigned short* wo_l   = wb16 + 11010048;
  unsigned short* w1_h   = wb16 + 12582912;
  unsigned short* w1_l   = wb16 + 18874368;
  unsigned short* w2_h   = wb16 + 25165824;
  unsigned short* w2_l   = wb16 + 31457280;
  unsigned short* wp_h   = wb16 + 37748736;
  unsigned short* wp_l   = wb16 + 37879808;
  unsigned short* wd1_h  = wb16 + 38010880;
  unsigned short* wd1_l  = wb16 + 38076416;
  unsigned short* scr    = wb16;   // JIT scratch (small mode)

  auto G = [&](int act, const float* A, const float* W, const float* bias,
               const float* resid, float* out, int M, int N, int K) {
    dim3 g(N / 64, M / 64), b(256);
    if (act == 0) hipLaunchKernelGGL((gemm3<0>), g, b, 0, stream, A, W, bias, resid, out, M, N, K);
    else if (act == 1) hipLaunchKernelGGL((gemm3<1>), g, b, 0, stream, A, W, bias, resid, out, M, N, K);
    else hipLaunchKernelGGL((gemm3<2>), g, b, 0, stream, A, W, bias, resid, out, M, N, K);
  };
  auto CONV = [&](const float* W, unsigned short* hi, unsigned short* lo,
                  int K, int N, int layers, long dls) {
    int blocks = ((K >> 3) * N + 255) / 256;
    hipLaunchKernelGGL(convw, dim3(blocks, layers), dim3(256), 0, stream, W, hi, lo, K, N, dls);
  };

  hipMemsetAsync(lacc, 0, 4 * sizeof(float), stream);
  if (bigws) {  // one-time full weight conversion
    CONV(Wq, wqkv_h,          wqkv_l,          512, 512, 6, 786432);
    CONV(Wk, wqkv_h + 262144, wqkv_l + 262144, 512, 512, 6, 786432);
    CONV(Wv, wqkv_h + 524288, wqkv_l + 524288, 512, 512, 6, 786432);
    CONV(Wo, wo_h, wo_l, 512, 512, 6, 262144);
    CONV(W1, w1_h, w1_l, 512, 2048, 6, 1048576);
    CONV(W2, w2_h, w2_l, 2048, 512, 6, 1048576);
    CONV(Wp, wp_h, wp_l, 512, 256, 1, 0);
    CONV(Wd1, wd1_h, wd1_l, 256, 256, 1, 0);
  }
  hipLaunchKernelGGL(bn_stats_kernel, dim3(64), dim3(256), 0, stream, tok, bn_g, bn_b, ss);
  hipLaunchKernelGGL(tn_kernel, dim3(1024), dim3(256), 0, stream, tok, ss, tn);
  G(0, tn, We, be, nullptr, x0, 4096, 512, 64);
  hipLaunchKernelGGL(reverse_kernel, dim3(8192), dim3(256), 0, stream, x0, x0r);

  for (int dir = 0; dir < 2; ++dir) {
    const float* xin = dir ? x0r : x0;
    for (int l = 0; l < 6; ++l) {
      const float* xl = (l == 0) ? xin : x;
      hipLaunchKernelGGL(ln_pl, dim3(512), dim3(256), 0, stream,
                         xl, ln1_g + l * 512, ln1_b + l * 512, hh, hl);
      // fused QKV GEMM, N=1536; attention-ready outputs (Q planes scaled, K planes, vT)
      const unsigned short *pqh, *pql;
      if (bigws) { pqh = wqkv_h + (size_t)l * 786432; pql = wqkv_l + (size_t)l * 786432; }
      else {
        CONV(Wq + (size_t)l * 262144, scr,          scr + 786432,          512, 512, 1, 0);
        CONV(Wk + (size_t)l * 262144, scr + 262144, scr + 786432 + 262144, 512, 512, 1, 0);
        CONV(Wv + (size_t)l * 262144, scr + 524288, scr + 786432 + 524288, 512, 512, 1, 0);
        pqh = scr; pql = scr + 786432;
      }
      hipLaunchKernelGGL((gemm_bf<0, 1, 0, 1, 1>), dim3(12, 32, 1), dim3(256), 0, stream,
                         hh, hl, pqh, pql, bq + l * 512, bk + l * 512, bv + l * 512,
                         nullptr, qkvh, qkvl, vth, vtl, 4096, 1536, 512, 512);
      // seed x with the residual for layer 0
      if (l == 0)
        hipMemcpyAsync(x, xin, 2097152 * sizeof(float), hipMemcpyDeviceToDevice, stream);
      hipLaunchKernelGGL(attn_mfma, dim3(512), dim3(256), 0, stream,
                         qkvh, qkvl, vth, vtl, mask, ybh, ybl, dir);
      // O-proj: split-K=2, atomicAdd into x (x pre-holds residual)
      const unsigned short *poh, *pol;
      if (bigws) { poh = wo_h + (size_t)l * 262144; pol = wo_l + (size_t)l * 262144; }
      else {
        CONV(Wo + (size_t)l * 262144, scr, scr + 262144, 512, 512, 1, 0);
        poh = scr; pol = scr + 262144;
      }
      hipLaunchKernelGGL((gemm_bf<0, 0, 1, 0, 0>), dim3(4, 32, 2), dim3(256), 0, stream,
                         ybh, ybl, poh, pol, bo + l * 512, nullptr, nullptr,
                         x, nullptr, nullptr, nullptr, nullptr, 4096, 512, 512, 256);
      hipLaunchKernelGGL(ln_pl, dim3(512), dim3(256), 0, stream,
                         x, ln2_g + l * 512, ln2_b + l * 512, hh, hl);
      // MLP up + gelu, planes out
      const unsigned short *p1h, *p1l;
      if (bigws) { p1h = w1_h + (size_t)l * 1048576; p1l = w1_l + (size_t)l * 1048576; }
      else {
        CONV(W1 + (size_t)l * 1048576, scr, scr + 1048576, 512, 2048, 1, 0);
        p1h = scr; p1l = scr + 1048576;
      }
      hipLaunchKernelGGL((gemm_bf<1, 1, 0, 0, 0>), dim3(16, 32, 1), dim3(256), 0, stream,
                         hh, hl, p1h, p1l, b1 + l * 2048, nullptr, nullptr,
                         nullptr, uh, ul, nullptr, nullptr, 4096, 2048, 512, 512);
      // MLP down: split-K=2, atomicAdd into x
      const unsigned short *p2h, *p2l;
      if (bigws) { p2h = w2_h + (size_t)l * 1048576; p2l = w2_l + (size_t)l * 1048576; }
      else {
        CONV(W2 + (size_t)l * 1048576, scr, scr + 1048576, 2048, 512, 1, 0);
        p2h = scr; p2l = scr + 1048576;
      }
      hipLaunchKernelGGL((gemm_bf<0, 0, 1, 0, 0>), dim3(4, 32, 2), dim3(256), 0, stream,
                         uh, ul, p2h, p2l, b2 + l * 512, nullptr, nullptr,
                         x, nullptr, nullptr, nullptr, nullptr, 4096, 512, 2048, 1024);
    }
    hipLaunchKernelGGL(ln_pl, dim3(512), dim3(256), 0, stream, x, lnf_g, lnf_b, hh, hl);
    // head projection (f32 + planes out) and decoder first layer (tanh)
    const unsigned short *pph, *ppl, *pdh, *pdl;
    if (bigws) { pph = wp_h; ppl = wp_l; }
    else { CONV(Wp, scr, scr + 131072, 512, 256, 1, 0); pph = scr; ppl = scr + 131072; }
    hipLaunchKernelGGL((gemm_bf<0, 2, 0, 0, 0>), dim3(2, 32, 1), dim3(256), 0, stream,
                       hh, hl, pph, ppl, bp, nullptr, nullptr,
                       xo, xoh, xol, nullptr, nullptr, 4096, 256, 512, 512);
    if (bigws) { pdh = wd1_h; pdl = wd1_l; }
    else { CONV(Wd1, scr, scr + 65536, 256, 256, 1, 0); pdh = scr; pdl = scr + 65536; }
    hipLaunchKernelGGL((gemm_bf<2, 0, 0, 0, 0>), dim3(2, 32, 1), dim3(256), 0, stream,
                       xoh, xol, pdh, pdl, bd1, nullptr, nullptr,
                       hd, nullptr, nullptr, nullptr, nullptr, 4096, 256, 256, 256);
    hipLaunchKernelGGL(ln_kernel, dim3(4096), dim3(256), 0, stream, hd, lnd_g, lnd_b, hd2, 256);
    G(0, hd2, Wd2, bd2, nullptr, pd, 4096, 64, 256);
    hipLaunchKernelGGL(loss_reg_kernel, dim3(256), dim3(256), 0, stream,
                       pd, tok, mask, lacc + (dir ? 1 : 0), dir);
    hipLaunchKernelGGL(frame_mean_kernel, dim3(512), dim3(256), 0, stream,
                       xo, xf, dir == 0 ? out_f : (float*)nullptr);
    G(2, xf, Wf1, bf1, nullptr, hf, 512, 256, 256);
    hipLaunchKernelGGL(ln_kernel, dim3(512), dim3(256), 0, stream, hf, lnfr_g, lnfr_b, hf2, 256);
    G(0, hf2, Wf2, bf2, nullptr, pf, 512, 512, 256);
    hipLaunchKernelGGL(loss_fr_kernel, dim3(256), dim3(256), 0, stream,
                       pf, tok, mask, lacc + (dir ? 3 : 2), dir);
  }
  hipLaunchKernelGGL(finalize_kernel, dim3(1), dim3(64), 0, stream, lacc, out_f);
}